// Round 2
// baseline (3078.429 us; speedup 1.0000x reference)
//
#include <hip/hip_runtime.h>
#include <hip/hip_bf16.h>

#define B_    8
#define N_    2048
#define CIN_  64
#define D_    128
#define DFF_  512
#define DOUT_ 256
#define S_    512
#define H_    4
#define HD_   32
#define EPS_  1e-5f

// ---------------------------------------------------------------------------
// Farthest point sampling: 1 block per batch, 256 threads, 8 points/thread.
// Replicates numpy f32 arithmetic exactly (no FMA contraction) and
// first-occurrence argmax. Also writes output 0 = new_xyz^T [B,3,S] (f32).
// ---------------------------------------------------------------------------
__global__ __launch_bounds__(256) void fps_kernel(const float* __restrict__ xyz,
                                                  int* __restrict__ idx_out,
                                                  float* __restrict__ out0) {
  const int b = blockIdx.x;
  const int t = threadIdx.x;
  const float* xb = xyz + (size_t)b * 3 * N_;
  float px[8], py[8], pz[8], dist[8];
#pragma unroll
  for (int j = 0; j < 8; j++) {
    int p = t + 256 * j;
    px[j] = xb[p];
    py[j] = xb[N_ + p];
    pz[j] = xb[2 * N_ + p];
    dist[j] = 1e10f;
  }
  __shared__ float wval[4];
  __shared__ int   widx[4];
  __shared__ int   s_far;
  int far = 0;
  for (int s = 0; s < S_; s++) {
    float cx = xb[far];
    float cy = xb[N_ + far];
    float cz = xb[2 * N_ + far];
    if (t == 0) {
      idx_out[b * S_ + s] = far;
      out0[(size_t)b * 3 * S_ + s]          = cx;
      out0[(size_t)b * 3 * S_ + S_ + s]     = cy;
      out0[(size_t)b * 3 * S_ + 2 * S_ + s] = cz;
    }
    float best = -1.0f;
    int bestp = 0;
#pragma unroll
    for (int j = 0; j < 8; j++) {
      float dx = __fsub_rn(px[j], cx);
      float dy = __fsub_rn(py[j], cy);
      float dz = __fsub_rn(pz[j], cz);
      float d = __fadd_rn(__fadd_rn(__fmul_rn(dx, dx), __fmul_rn(dy, dy)),
                          __fmul_rn(dz, dz));
      float nd = fminf(dist[j], d);
      dist[j] = nd;
      if (nd > best) { best = nd; bestp = t + 256 * j; }  // ascending p keeps first max
    }
#pragma unroll
    for (int msk = 1; msk < 64; msk <<= 1) {
      float ov = __shfl_xor(best, msk);
      int   op = __shfl_xor(bestp, msk);
      if (ov > best || (ov == best && op < bestp)) { best = ov; bestp = op; }
    }
    if ((t & 63) == 0) { wval[t >> 6] = best; widx[t >> 6] = bestp; }
    __syncthreads();
    if (t == 0) {
#pragma unroll
      for (int w = 1; w < 4; w++) {
        if (wval[w] > best || (wval[w] == best && widx[w] < bestp)) {
          best = wval[w]; bestp = widx[w];
        }
      }
      s_far = bestp;
    }
    __syncthreads();
    far = s_far;
  }
}

// ---------------------------------------------------------------------------
// x = BN1(W_proj @ points + b_proj) + (W_pos @ xyz + b_pos), [B,N,D] f32
// ---------------------------------------------------------------------------
__global__ __launch_bounds__(128) void xfeat_kernel(
    const float* __restrict__ points, const float* __restrict__ xyz,
    const float* __restrict__ Wp, const float* __restrict__ bp,
    const float* __restrict__ g1, const float* __restrict__ be1,
    const float* __restrict__ m1, const float* __restrict__ v1,
    const float* __restrict__ Wpos, const float* __restrict__ bpos,
    float* __restrict__ xout) {
  const int token = blockIdx.x;
  const int b = token >> 11, n = token & (N_ - 1);
  const int d = threadIdx.x;
  __shared__ float pc[CIN_];
  __shared__ float xc[3];
  if (d < CIN_) pc[d] = points[((size_t)b * CIN_ + d) * N_ + n];
  if (d >= 64 && d < 67) xc[d - 64] = xyz[((size_t)b * 3 + (d - 64)) * N_ + n];
  __syncthreads();
  float acc = 0.f;
  for (int c = 0; c < CIN_; c++) acc += Wp[d * CIN_ + c] * pc[c];
  acc += bp[d];
  acc = (acc - m1[d]) * rsqrtf(v1[d] + EPS_) * g1[d] + be1[d];
  float pos = bpos[d];
#pragma unroll
  for (int c = 0; c < 3; c++) pos += Wpos[d * 3 + c] * xc[c];
  xout[(size_t)token * D_ + d] = acc + pos;
}

// ---------------------------------------------------------------------------
// q,k,v projections, stored [B,H,N,hd] f32
// ---------------------------------------------------------------------------
__global__ __launch_bounds__(128) void qkv_kernel(
    const float* __restrict__ x,
    const float* __restrict__ Wq, const float* __restrict__ bq,
    const float* __restrict__ Wk, const float* __restrict__ bk,
    const float* __restrict__ Wv, const float* __restrict__ bv,
    float* __restrict__ q, float* __restrict__ k, float* __restrict__ v) {
  const int token = blockIdx.x;
  const int d = threadIdx.x;
  __shared__ float xs[D_];
  xs[d] = x[(size_t)token * D_ + d];
  __syncthreads();
  float aq = bq[d], ak = bk[d], av = bv[d];
  for (int e = 0; e < D_; e++) {
    float xv = xs[e];
    aq += Wq[d * D_ + e] * xv;
    ak += Wk[d * D_ + e] * xv;
    av += Wv[d * D_ + e] * xv;
  }
  const int b = token >> 11, n = token & (N_ - 1);
  const int h = d >> 5, c = d & 31;
  const size_t oidx = (((size_t)(b * H_ + h) * N_ + n) * HD_) + c;
  q[oidx] = aq; k[oidx] = ak; v[oidx] = av;
}

// ---------------------------------------------------------------------------
// Flash-style attention, f32. Block = 16 query rows; row = 16 lanes.
// Online softmax over 32 chunks of 64 keys. o stored [B,N,D] f32.
// ---------------------------------------------------------------------------
__global__ __launch_bounds__(256) void attn_kernel(const float* __restrict__ q,
                                                   const float* __restrict__ k,
                                                   const float* __restrict__ v,
                                                   float* __restrict__ o) {
  const int bid = blockIdx.x;
  const int ntile = bid & 127;
  const int bh = bid >> 7;
  const int b = bh >> 2, h = bh & 3;
  const int t = threadIdx.x;
  const int r = t >> 4, l = t & 15;
  const float scale = 0.1767766952966369f;  // 1/sqrt(32)
  __shared__ float qs[16][33];
  __shared__ float ks[64][33];
  __shared__ float vs[64][32];
  __shared__ float ps[16][65];
  const float* qb = q + ((size_t)bh * N_ + ntile * 16) * HD_;
  const float* kb = k + (size_t)bh * N_ * HD_;
  const float* vb = v + (size_t)bh * N_ * HD_;
  for (int i = t; i < 16 * 32; i += 256) qs[i >> 5][i & 31] = qb[i];
  float mrun = -INFINITY, lrun = 0.f, a0 = 0.f, a1 = 0.f;
  for (int ch = 0; ch < 32; ch++) {
    __syncthreads();  // prev PV done reading ks/vs/ps; also covers qs on ch==0
    for (int i = t; i < 64 * 32; i += 256) {
      int m = i >> 5, c = i & 31;
      ks[m][c] = kb[ch * 2048 + i];
      vs[m][c] = vb[ch * 2048 + i];
    }
    __syncthreads();
    float p[4];
    float mx = -INFINITY;
#pragma unroll
    for (int i = 0; i < 4; i++) {
      int m = l + 16 * i;
      float s = 0.f;
#pragma unroll
      for (int c = 0; c < 32; c++) s += qs[r][c] * ks[m][c];
      s *= scale;
      p[i] = s;
      mx = fmaxf(mx, s);
    }
#pragma unroll
    for (int msk = 1; msk < 16; msk <<= 1) mx = fmaxf(mx, __shfl_xor(mx, msk));
    float newm = fmaxf(mrun, mx);
    float alpha = __expf(mrun - newm);
    float psum = 0.f;
#pragma unroll
    for (int i = 0; i < 4; i++) { p[i] = __expf(p[i] - newm); psum += p[i]; }
#pragma unroll
    for (int msk = 1; msk < 16; msk <<= 1) psum += __shfl_xor(psum, msk);
    lrun = lrun * alpha + psum;
    mrun = newm;
    a0 *= alpha; a1 *= alpha;
#pragma unroll
    for (int i = 0; i < 4; i++) ps[r][l + 16 * i] = p[i];
    __syncthreads();
#pragma unroll 4
    for (int m = 0; m < 64; m++) {
      float pm = ps[r][m];
      a0 += pm * vs[m][l];
      a1 += pm * vs[m][l + 16];
    }
  }
  const int n = ntile * 16 + r;
  float* ob = o + ((size_t)b * N_ + n) * D_ + h * HD_;
  ob[l]      = a0 / lrun;
  ob[l + 16] = a1 / lrun;
}

// ---------------------------------------------------------------------------
// x2 = LN1(x + o @ Wo^T + bo)
// ---------------------------------------------------------------------------
__global__ __launch_bounds__(128) void oln1_kernel(
    const float* __restrict__ o, const float* __restrict__ x,
    const float* __restrict__ Wo, const float* __restrict__ bo,
    const float* __restrict__ g, const float* __restrict__ be,
    float* __restrict__ x2) {
  const int token = blockIdx.x;
  const int d = threadIdx.x;
  __shared__ float os[D_];
  __shared__ float red[2];
  os[d] = o[(size_t)token * D_ + d];
  __syncthreads();
  float acc = bo[d];
  for (int e = 0; e < D_; e++) acc += Wo[d * D_ + e] * os[e];
  float val = x[(size_t)token * D_ + d] + acc;
  float s = val;
#pragma unroll
  for (int msk = 1; msk < 64; msk <<= 1) s += __shfl_xor(s, msk);
  if ((d & 63) == 0) red[d >> 6] = s;
  __syncthreads();
  float mu = (red[0] + red[1]) * (1.f / 128.f);
  float df = val - mu;
  float s2 = df * df;
#pragma unroll
  for (int msk = 1; msk < 64; msk <<= 1) s2 += __shfl_xor(s2, msk);
  __syncthreads();
  if ((d & 63) == 0) red[d >> 6] = s2;
  __syncthreads();
  float var = (red[0] + red[1]) * (1.f / 128.f);
  x2[(size_t)token * D_ + d] = df * rsqrtf(var + EPS_) * g[d] + be[d];
}

// ---------------------------------------------------------------------------
// h = relu(x2 @ W1^T + b1), [B,N,Dff]
// ---------------------------------------------------------------------------
__global__ __launch_bounds__(256) void ffn1_kernel(
    const float* __restrict__ x2, const float* __restrict__ W1,
    const float* __restrict__ b1, float* __restrict__ h) {
  const int token = blockIdx.x;
  const int t = threadIdx.x;
  __shared__ float xs[D_];
  if (t < D_) xs[t] = x2[(size_t)token * D_ + t];
  __syncthreads();
#pragma unroll
  for (int fi = 0; fi < 2; fi++) {
    int f = t + fi * 256;
    float acc = b1[f];
    for (int d = 0; d < D_; d++) acc += W1[f * D_ + d] * xs[d];
    h[(size_t)token * DFF_ + f] = fmaxf(acc, 0.f);
  }
}

// ---------------------------------------------------------------------------
// features = LN2(x2 + h @ W2^T + b2)
// ---------------------------------------------------------------------------
__global__ __launch_bounds__(128) void ffn2ln_kernel(
    const float* __restrict__ h, const float* __restrict__ x2,
    const float* __restrict__ W2, const float* __restrict__ b2p,
    const float* __restrict__ g, const float* __restrict__ be,
    float* __restrict__ feats) {
  const int token = blockIdx.x;
  const int d = threadIdx.x;
  __shared__ float hs[DFF_];
  __shared__ float red[2];
  for (int i = d; i < DFF_; i += 128) hs[i] = h[(size_t)token * DFF_ + i];
  __syncthreads();
  float acc = b2p[d];
  for (int f = 0; f < DFF_; f++) acc += W2[d * DFF_ + f] * hs[f];
  float val = x2[(size_t)token * D_ + d] + acc;
  float s = val;
#pragma unroll
  for (int msk = 1; msk < 64; msk <<= 1) s += __shfl_xor(s, msk);
  if ((d & 63) == 0) red[d >> 6] = s;
  __syncthreads();
  float mu = (red[0] + red[1]) * (1.f / 128.f);
  float df = val - mu;
  float s2 = df * df;
#pragma unroll
  for (int msk = 1; msk < 64; msk <<= 1) s2 += __shfl_xor(s2, msk);
  __syncthreads();
  if ((d & 63) == 0) red[d >> 6] = s2;
  __syncthreads();
  float var = (red[0] + red[1]) * (1.f / 128.f);
  feats[(size_t)token * D_ + d] = df * rsqrtf(var + EPS_) * g[d] + be[d];
}

// ---------------------------------------------------------------------------
// gather at fps idx, concat xyz, FC + BN2 + relu -> out1 [B,Dout,S] f32
// ---------------------------------------------------------------------------
__global__ __launch_bounds__(256) void gatherfc_kernel(
    const float* __restrict__ feats, const float* __restrict__ xyz,
    const int* __restrict__ fps_idx,
    const float* __restrict__ Wfc, const float* __restrict__ bfc,
    const float* __restrict__ g2, const float* __restrict__ bb2,
    const float* __restrict__ m2, const float* __restrict__ v2,
    float* __restrict__ out1) {
  const int bid = blockIdx.x;
  const int b = bid >> 9, s = bid & (S_ - 1);
  const int t = threadIdx.x;
  __shared__ float cat[131];
  const int id = fps_idx[b * S_ + s];
  if (t < D_) cat[t] = feats[((size_t)b * N_ + id) * D_ + t];
  if (t >= 128 && t < 131) cat[t] = xyz[((size_t)b * 3 + (t - 128)) * N_ + id];
  __syncthreads();
  float acc = bfc[t];
  for (int j = 0; j < 131; j++) acc += Wfc[t * 131 + j] * cat[j];
  acc = (acc - m2[t]) * rsqrtf(v2[t] + EPS_) * g2[t] + bb2[t];
  acc = fmaxf(acc, 0.f);
  out1[((size_t)b * DOUT_ + t) * S_ + s] = acc;
}

// ---------------------------------------------------------------------------
extern "C" void kernel_launch(void* const* d_in, const int* in_sizes, int n_in,
                              void* d_out, int out_size, void* d_ws, size_t ws_size,
                              hipStream_t stream) {
  const float* xyz    = (const float*)d_in[0];
  const float* points = (const float*)d_in[1];
  const float* Wp     = (const float*)d_in[2];
  const float* bp     = (const float*)d_in[3];
  const float* g1     = (const float*)d_in[4];
  const float* be1    = (const float*)d_in[5];
  const float* m1     = (const float*)d_in[6];
  const float* v1     = (const float*)d_in[7];
  const float* Wpos   = (const float*)d_in[8];
  const float* bpos   = (const float*)d_in[9];
  const float* Wq     = (const float*)d_in[10];
  const float* bq     = (const float*)d_in[11];
  const float* Wk     = (const float*)d_in[12];
  const float* bk     = (const float*)d_in[13];
  const float* Wv     = (const float*)d_in[14];
  const float* bv     = (const float*)d_in[15];
  const float* Wo     = (const float*)d_in[16];
  const float* bo     = (const float*)d_in[17];
  const float* lg1    = (const float*)d_in[18];
  const float* lb1    = (const float*)d_in[19];
  const float* W1     = (const float*)d_in[20];
  const float* b1     = (const float*)d_in[21];
  const float* W2     = (const float*)d_in[22];
  const float* b2p    = (const float*)d_in[23];
  const float* lg2    = (const float*)d_in[24];
  const float* lb2    = (const float*)d_in[25];
  const float* Wfc    = (const float*)d_in[26];
  const float* bfc    = (const float*)d_in[27];
  const float* g2     = (const float*)d_in[28];
  const float* bb2    = (const float*)d_in[29];
  const float* m2     = (const float*)d_in[30];
  const float* v2     = (const float*)d_in[31];

  float* out0 = (float*)d_out;               // [B,3,S]
  float* out1 = out0 + (size_t)B_ * 3 * S_;  // [B,Dout,S]

  char* ws = (char*)d_ws;
  int*   fps_idx = (int*)ws;                 // B*S ints = 16 KB
  float* x  = (float*)(ws + 16384);
  const size_t BND = (size_t)B_ * N_ * D_;
  float* q  = x + BND;
  float* k  = q + BND;
  float* v  = k + BND;
  float* o  = v + BND;
  float* x2 = o + BND;
  float* h  = q;      // reuse q..o region (4*BND floats = B*N*Dff)
  float* feats = x;   // reuse x region

  fps_kernel<<<B_, 256, 0, stream>>>(xyz, fps_idx, out0);
  xfeat_kernel<<<B_ * N_, 128, 0, stream>>>(points, xyz, Wp, bp, g1, be1, m1, v1,
                                            Wpos, bpos, x);
  qkv_kernel<<<B_ * N_, 128, 0, stream>>>(x, Wq, bq, Wk, bk, Wv, bv, q, k, v);
  attn_kernel<<<B_ * H_ * (N_ / 16), 256, 0, stream>>>(q, k, v, o);
  oln1_kernel<<<B_ * N_, 128, 0, stream>>>(o, x, Wo, bo, lg1, lb1, x2);
  ffn1_kernel<<<B_ * N_, 256, 0, stream>>>(x2, W1, b1, h);
  ffn2ln_kernel<<<B_ * N_, 128, 0, stream>>>(h, x2, W2, b2p, lg2, lb2, feats);
  gatherfc_kernel<<<B_ * S_, 256, 0, stream>>>(feats, xyz, fps_idx, Wfc, bfc,
                                               g2, bb2, m2, v2, out1);
}

// Round 3
// 2357.401 us; speedup vs baseline: 1.3059x; 1.3059x over previous
//
#include <hip/hip_runtime.h>
#include <hip/hip_bf16.h>

#define B_    8
#define N_    2048
#define CIN_  64
#define D_    128
#define DFF_  512
#define DOUT_ 256
#define S_    512
#define H_    4
#define HD_   32
#define EPS_  1e-5f

typedef __attribute__((ext_vector_type(8))) short short8v;  // 8 bf16 (4 VGPRs)
typedef __attribute__((ext_vector_type(4))) float f32x4;

// ---------------------------------------------------------------------------
// Farthest point sampling: 1 block per batch, 256 threads, 8 points/thread.
// Replicates numpy f32 arithmetic exactly (no FMA contraction) and
// first-occurrence argmax. Also writes output 0 = new_xyz^T [B,3,S] (f32).
// ---------------------------------------------------------------------------
__global__ __launch_bounds__(256) void fps_kernel(const float* __restrict__ xyz,
                                                  int* __restrict__ idx_out,
                                                  float* __restrict__ out0) {
  const int b = blockIdx.x;
  const int t = threadIdx.x;
  const float* xb = xyz + (size_t)b * 3 * N_;
  float px[8], py[8], pz[8], dist[8];
#pragma unroll
  for (int j = 0; j < 8; j++) {
    int p = t + 256 * j;
    px[j] = xb[p];
    py[j] = xb[N_ + p];
    pz[j] = xb[2 * N_ + p];
    dist[j] = 1e10f;
  }
  __shared__ float wval[4];
  __shared__ int   widx[4];
  __shared__ int   s_far;
  int far = 0;
  for (int s = 0; s < S_; s++) {
    float cx = xb[far];
    float cy = xb[N_ + far];
    float cz = xb[2 * N_ + far];
    if (t == 0) {
      idx_out[b * S_ + s] = far;
      out0[(size_t)b * 3 * S_ + s]          = cx;
      out0[(size_t)b * 3 * S_ + S_ + s]     = cy;
      out0[(size_t)b * 3 * S_ + 2 * S_ + s] = cz;
    }
    float best = -1.0f;
    int bestp = 0;
#pragma unroll
    for (int j = 0; j < 8; j++) {
      float dx = __fsub_rn(px[j], cx);
      float dy = __fsub_rn(py[j], cy);
      float dz = __fsub_rn(pz[j], cz);
      float d = __fadd_rn(__fadd_rn(__fmul_rn(dx, dx), __fmul_rn(dy, dy)),
                          __fmul_rn(dz, dz));
      float nd = fminf(dist[j], d);
      dist[j] = nd;
      if (nd > best) { best = nd; bestp = t + 256 * j; }
    }
#pragma unroll
    for (int msk = 1; msk < 64; msk <<= 1) {
      float ov = __shfl_xor(best, msk);
      int   op = __shfl_xor(bestp, msk);
      if (ov > best || (ov == best && op < bestp)) { best = ov; bestp = op; }
    }
    if ((t & 63) == 0) { wval[t >> 6] = best; widx[t >> 6] = bestp; }
    __syncthreads();
    if (t == 0) {
#pragma unroll
      for (int w = 1; w < 4; w++) {
        if (wval[w] > best || (wval[w] == best && widx[w] < bestp)) {
          best = wval[w]; bestp = widx[w];
        }
      }
      s_far = bestp;
    }
    __syncthreads();
    far = s_far;
  }
}

// ---------------------------------------------------------------------------
// x = BN1(W_proj @ points + b_proj) + (W_pos @ xyz + b_pos), [B,N,D] f32
// ---------------------------------------------------------------------------
__global__ __launch_bounds__(128) void xfeat_kernel(
    const float* __restrict__ points, const float* __restrict__ xyz,
    const float* __restrict__ Wp, const float* __restrict__ bp,
    const float* __restrict__ g1, const float* __restrict__ be1,
    const float* __restrict__ m1, const float* __restrict__ v1,
    const float* __restrict__ Wpos, const float* __restrict__ bpos,
    float* __restrict__ xout) {
  const int token = blockIdx.x;
  const int b = token >> 11, n = token & (N_ - 1);
  const int d = threadIdx.x;
  __shared__ float pc[CIN_];
  __shared__ float xc[3];
  if (d < CIN_) pc[d] = points[((size_t)b * CIN_ + d) * N_ + n];
  if (d >= 64 && d < 67) xc[d - 64] = xyz[((size_t)b * 3 + (d - 64)) * N_ + n];
  __syncthreads();
  float acc = 0.f;
  for (int c = 0; c < CIN_; c++) acc += Wp[d * CIN_ + c] * pc[c];
  acc += bp[d];
  acc = (acc - m1[d]) * rsqrtf(v1[d] + EPS_) * g1[d] + be1[d];
  float pos = bpos[d];
#pragma unroll
  for (int c = 0; c < 3; c++) pos += Wpos[d * 3 + c] * xc[c];
  xout[(size_t)token * D_ + d] = acc + pos;
}

// ---------------------------------------------------------------------------
// q,k,v projections -> bf16 [B,H,N,hd]; q pre-scaled by 1/sqrt(hd)
// ---------------------------------------------------------------------------
__global__ __launch_bounds__(128) void qkv_kernel(
    const float* __restrict__ x,
    const float* __restrict__ Wq, const float* __restrict__ bq,
    const float* __restrict__ Wk, const float* __restrict__ bk,
    const float* __restrict__ Wv, const float* __restrict__ bv,
    __hip_bfloat16* __restrict__ q, __hip_bfloat16* __restrict__ k,
    __hip_bfloat16* __restrict__ v) {
  const int token = blockIdx.x;
  const int d = threadIdx.x;
  __shared__ float xs[D_];
  xs[d] = x[(size_t)token * D_ + d];
  __syncthreads();
  float aq = bq[d], ak = bk[d], av = bv[d];
  for (int e = 0; e < D_; e++) {
    float xv = xs[e];
    aq += Wq[d * D_ + e] * xv;
    ak += Wk[d * D_ + e] * xv;
    av += Wv[d * D_ + e] * xv;
  }
  const int b = token >> 11, n = token & (N_ - 1);
  const int h = d >> 5, c = d & 31;
  const size_t oidx = (((size_t)(b * H_ + h) * N_ + n) * HD_) + c;
  q[oidx] = __float2bfloat16(aq * 0.1767766952966369f);  // fold 1/sqrt(32)
  k[oidx] = __float2bfloat16(ak);
  v[oidx] = __float2bfloat16(av);
}

// ---------------------------------------------------------------------------
// Flash attention with bf16 MFMA (16x16x32: K = head_dim = 32 in one shot).
// Grid: 32 (b,h) x 16 q-tiles of 128 rows. Block: 4 waves, 32 q-rows/wave.
// Frag contract (m89/m92-verified): A a[e]=A[l&15][8*(l>>4)+e];
// B b[e]=B[8*(l>>4)+e][l&15]; D d[i]=D[4*(l>>4)+i][l&15].
// ---------------------------------------------------------------------------
__global__ __launch_bounds__(256) void attn_mfma_kernel(
    const unsigned short* __restrict__ qg, const unsigned short* __restrict__ kg,
    const unsigned short* __restrict__ vg, float* __restrict__ o) {
  const int bid = blockIdx.x;
  const int qt = bid & 15;
  const int bh = bid >> 4;
  const int b = bh >> 2, h = bh & 3;
  const int t = threadIdx.x;
  const int w = t >> 6, lane = t & 63, g = lane >> 4, lr = lane & 15;

  __shared__ __align__(16) unsigned short ks[64][40];     // K chunk, +pad
  __shared__ __align__(16) unsigned short vt[32][72];     // V^T chunk, +pad
  __shared__ __align__(16) unsigned short ps[4][32][72];  // per-wave P tile

  const int qbase = qt * 128 + w * 32;
  const unsigned short* qrow = qg + ((size_t)bh * N_ + qbase) * HD_;
  short8v aq[2];
#pragma unroll
  for (int qf = 0; qf < 2; qf++)
    aq[qf] = *(const short8v*)(qrow + (qf * 16 + lr) * HD_ + 8 * g);

  const unsigned short* kb = kg + (size_t)bh * N_ * HD_;
  const unsigned short* vb = vg + (size_t)bh * N_ * HD_;

  const f32x4 fzero = {0.f, 0.f, 0.f, 0.f};
  float mrun[2][4], lrun[2][4];
  f32x4 acco[2][2];
#pragma unroll
  for (int qf = 0; qf < 2; qf++) {
#pragma unroll
    for (int i = 0; i < 4; i++) { mrun[qf][i] = -INFINITY; lrun[qf][i] = 0.f; }
    acco[qf][0] = fzero;
    acco[qf][1] = fzero;
  }

  const int srow = t >> 2, scol = (t & 3) * 8;  // staging: 8 bf16 per thread

  for (int ch = 0; ch < 32; ch++) {
    __syncthreads();  // prev chunk's MFMA reads of ks/vt are done block-wide
    short8v kvv = *(const short8v*)(kb + (size_t)(ch * 64 + srow) * HD_ + scol);
    short8v vvv = *(const short8v*)(vb + (size_t)(ch * 64 + srow) * HD_ + scol);
    *(short8v*)(&ks[srow][scol]) = kvv;
#pragma unroll
    for (int e = 0; e < 8; e++) vt[scol + e][srow] = (unsigned short)vvv[e];
    __syncthreads();

    // S = Q * K^T  (q pre-scaled by 1/sqrt(hd))
    f32x4 s[2][4];
#pragma unroll
    for (int qf = 0; qf < 2; qf++)
#pragma unroll
      for (int kt = 0; kt < 4; kt++) {
        short8v bk = *(const short8v*)(&ks[kt * 16 + lr][8 * g]);
        s[qf][kt] =
            __builtin_amdgcn_mfma_f32_16x16x32_bf16(aq[qf], bk, fzero, 0, 0, 0);
      }

    // online softmax; write P (bf16) to per-wave LDS tile
#pragma unroll
    for (int qf = 0; qf < 2; qf++) {
#pragma unroll
      for (int i = 0; i < 4; i++) {
        float mx = fmaxf(fmaxf(s[qf][0][i], s[qf][1][i]),
                         fmaxf(s[qf][2][i], s[qf][3][i]));
#pragma unroll
        for (int m = 1; m < 16; m <<= 1) mx = fmaxf(mx, __shfl_xor(mx, m));
        float nm = fmaxf(mrun[qf][i], mx);
        float alpha = __expf(mrun[qf][i] - nm);
        mrun[qf][i] = nm;
        float psum = 0.f;
#pragma unroll
        for (int kt = 0; kt < 4; kt++) {
          float pv = __expf(s[qf][kt][i] - nm);
          psum += pv;
          __hip_bfloat16 hb = __float2bfloat16(pv);
          ps[w][qf * 16 + 4 * g + i][kt * 16 + lr] = *(unsigned short*)&hb;
        }
#pragma unroll
        for (int m = 1; m < 16; m <<= 1) psum += __shfl_xor(psum, m);
        lrun[qf][i] = lrun[qf][i] * alpha + psum;
        acco[qf][0][i] *= alpha;
        acco[qf][1][i] *= alpha;
      }
    }

    // O += P * V   (within-wave LDS write->read; compiler inserts lgkmcnt)
#pragma unroll
    for (int qf = 0; qf < 2; qf++)
#pragma unroll
      for (int mc = 0; mc < 2; mc++) {
        short8v pa = *(const short8v*)(&ps[w][qf * 16 + lr][mc * 32 + 8 * g]);
#pragma unroll
        for (int dt = 0; dt < 2; dt++) {
          short8v bv = *(const short8v*)(&vt[dt * 16 + lr][mc * 32 + 8 * g]);
          acco[qf][dt] = __builtin_amdgcn_mfma_f32_16x16x32_bf16(
              pa, bv, acco[qf][dt], 0, 0, 0);
        }
      }
  }

#pragma unroll
  for (int qf = 0; qf < 2; qf++)
#pragma unroll
    for (int dt = 0; dt < 2; dt++)
#pragma unroll
      for (int i = 0; i < 4; i++) {
        int row = qbase + qf * 16 + 4 * g + i;
        o[((size_t)b * N_ + row) * D_ + h * HD_ + dt * 16 + lr] =
            acco[qf][dt][i] / lrun[qf][i];
      }
}

// ---------------------------------------------------------------------------
// x2 = LN1(x + o @ Wo^T + bo)
// ---------------------------------------------------------------------------
__global__ __launch_bounds__(128) void oln1_kernel(
    const float* __restrict__ o, const float* __restrict__ x,
    const float* __restrict__ Wo, const float* __restrict__ bo,
    const float* __restrict__ g, const float* __restrict__ be,
    float* __restrict__ x2) {
  const int token = blockIdx.x;
  const int d = threadIdx.x;
  __shared__ float os[D_];
  __shared__ float red[2];
  os[d] = o[(size_t)token * D_ + d];
  __syncthreads();
  float acc = bo[d];
  for (int e = 0; e < D_; e++) acc += Wo[d * D_ + e] * os[e];
  float val = x[(size_t)token * D_ + d] + acc;
  float s = val;
#pragma unroll
  for (int msk = 1; msk < 64; msk <<= 1) s += __shfl_xor(s, msk);
  if ((d & 63) == 0) red[d >> 6] = s;
  __syncthreads();
  float mu = (red[0] + red[1]) * (1.f / 128.f);
  float df = val - mu;
  float s2 = df * df;
#pragma unroll
  for (int msk = 1; msk < 64; msk <<= 1) s2 += __shfl_xor(s2, msk);
  __syncthreads();
  if ((d & 63) == 0) red[d >> 6] = s2;
  __syncthreads();
  float var = (red[0] + red[1]) * (1.f / 128.f);
  x2[(size_t)token * D_ + d] = df * rsqrtf(var + EPS_) * g[d] + be[d];
}

// ---------------------------------------------------------------------------
// h = relu(x2 @ W1^T + b1), [B,N,Dff]
// ---------------------------------------------------------------------------
__global__ __launch_bounds__(256) void ffn1_kernel(
    const float* __restrict__ x2, const float* __restrict__ W1,
    const float* __restrict__ b1, float* __restrict__ h) {
  const int token = blockIdx.x;
  const int t = threadIdx.x;
  __shared__ float xs[D_];
  if (t < D_) xs[t] = x2[(size_t)token * D_ + t];
  __syncthreads();
#pragma unroll
  for (int fi = 0; fi < 2; fi++) {
    int f = t + fi * 256;
    float acc = b1[f];
    for (int d = 0; d < D_; d++) acc += W1[f * D_ + d] * xs[d];
    h[(size_t)token * DFF_ + f] = fmaxf(acc, 0.f);
  }
}

// ---------------------------------------------------------------------------
// features = LN2(x2 + h @ W2^T + b2)
// ---------------------------------------------------------------------------
__global__ __launch_bounds__(128) void ffn2ln_kernel(
    const float* __restrict__ h, const float* __restrict__ x2,
    const float* __restrict__ W2, const float* __restrict__ b2p,
    const float* __restrict__ g, const float* __restrict__ be,
    float* __restrict__ feats) {
  const int token = blockIdx.x;
  const int d = threadIdx.x;
  __shared__ float hs[DFF_];
  __shared__ float red[2];
  for (int i = d; i < DFF_; i += 128) hs[i] = h[(size_t)token * DFF_ + i];
  __syncthreads();
  float acc = b2p[d];
  for (int f = 0; f < DFF_; f++) acc += W2[d * DFF_ + f] * hs[f];
  float val = x2[(size_t)token * D_ + d] + acc;
  float s = val;
#pragma unroll
  for (int msk = 1; msk < 64; msk <<= 1) s += __shfl_xor(s, msk);
  if ((d & 63) == 0) red[d >> 6] = s;
  __syncthreads();
  float mu = (red[0] + red[1]) * (1.f / 128.f);
  float df = val - mu;
  float s2 = df * df;
#pragma unroll
  for (int msk = 1; msk < 64; msk <<= 1) s2 += __shfl_xor(s2, msk);
  __syncthreads();
  if ((d & 63) == 0) red[d >> 6] = s2;
  __syncthreads();
  float var = (red[0] + red[1]) * (1.f / 128.f);
  feats[(size_t)token * D_ + d] = df * rsqrtf(var + EPS_) * g[d] + be[d];
}

// ---------------------------------------------------------------------------
// gather at fps idx, concat xyz, FC + BN2 + relu -> out1 [B,Dout,S] f32
// ---------------------------------------------------------------------------
__global__ __launch_bounds__(256) void gatherfc_kernel(
    const float* __restrict__ feats, const float* __restrict__ xyz,
    const int* __restrict__ fps_idx,
    const float* __restrict__ Wfc, const float* __restrict__ bfc,
    const float* __restrict__ g2, const float* __restrict__ bb2,
    const float* __restrict__ m2, const float* __restrict__ v2,
    float* __restrict__ out1) {
  const int bid = blockIdx.x;
  const int b = bid >> 9, s = bid & (S_ - 1);
  const int t = threadIdx.x;
  __shared__ float cat[131];
  const int id = fps_idx[b * S_ + s];
  if (t < D_) cat[t] = feats[((size_t)b * N_ + id) * D_ + t];
  if (t >= 128 && t < 131) cat[t] = xyz[((size_t)b * 3 + (t - 128)) * N_ + id];
  __syncthreads();
  float acc = bfc[t];
  for (int j = 0; j < 131; j++) acc += Wfc[t * 131 + j] * cat[j];
  acc = (acc - m2[t]) * rsqrtf(v2[t] + EPS_) * g2[t] + bb2[t];
  acc = fmaxf(acc, 0.f);
  out1[((size_t)b * DOUT_ + t) * S_ + s] = acc;
}

// ---------------------------------------------------------------------------
extern "C" void kernel_launch(void* const* d_in, const int* in_sizes, int n_in,
                              void* d_out, int out_size, void* d_ws, size_t ws_size,
                              hipStream_t stream) {
  const float* xyz    = (const float*)d_in[0];
  const float* points = (const float*)d_in[1];
  const float* Wp     = (const float*)d_in[2];
  const float* bp     = (const float*)d_in[3];
  const float* g1     = (const float*)d_in[4];
  const float* be1    = (const float*)d_in[5];
  const float* m1     = (const float*)d_in[6];
  const float* v1     = (const float*)d_in[7];
  const float* Wpos   = (const float*)d_in[8];
  const float* bpos   = (const float*)d_in[9];
  const float* Wq     = (const float*)d_in[10];
  const float* bq     = (const float*)d_in[11];
  const float* Wk     = (const float*)d_in[12];
  const float* bk     = (const float*)d_in[13];
  const float* Wv     = (const float*)d_in[14];
  const float* bv     = (const float*)d_in[15];
  const float* Wo     = (const float*)d_in[16];
  const float* bo     = (const float*)d_in[17];
  const float* lg1    = (const float*)d_in[18];
  const float* lb1    = (const float*)d_in[19];
  const float* W1     = (const float*)d_in[20];
  const float* b1     = (const float*)d_in[21];
  const float* W2     = (const float*)d_in[22];
  const float* b2p    = (const float*)d_in[23];
  const float* lg2    = (const float*)d_in[24];
  const float* lb2    = (const float*)d_in[25];
  const float* Wfc    = (const float*)d_in[26];
  const float* bfc    = (const float*)d_in[27];
  const float* g2     = (const float*)d_in[28];
  const float* bb2    = (const float*)d_in[29];
  const float* m2     = (const float*)d_in[30];
  const float* v2     = (const float*)d_in[31];

  float* out0 = (float*)d_out;               // [B,3,S]
  float* out1 = out0 + (size_t)B_ * 3 * S_;  // [B,Dout,S]

  char* ws = (char*)d_ws;
  int*   fps_idx = (int*)ws;                 // 16 KB
  const size_t BND = (size_t)B_ * N_ * D_;   // 2,097,152
  float* x  = (float*)(ws + 16384);          // 8 MB
  float* x2 = x + BND;                       // 8 MB
  float* o  = x2 + BND;                      // 8 MB
  __hip_bfloat16* qb = (__hip_bfloat16*)(o + BND);  // 4 MB
  __hip_bfloat16* kb = qb + BND;                    // 4 MB
  __hip_bfloat16* vb = kb + BND;                    // 4 MB
  float* h = o;       // overlays o/qb/kb/vb + 12 MB beyond (o,qkv dead by then)
  float* feats = x;   // x dead after oln1

  fps_kernel<<<B_, 256, 0, stream>>>(xyz, fps_idx, out0);
  xfeat_kernel<<<B_ * N_, 128, 0, stream>>>(points, xyz, Wp, bp, g1, be1, m1, v1,
                                            Wpos, bpos, x);
  qkv_kernel<<<B_ * N_, 128, 0, stream>>>(x, Wq, bq, Wk, bk, Wv, bv, qb, kb, vb);
  attn_mfma_kernel<<<B_ * H_ * (N_ / 128), 256, 0, stream>>>(
      (const unsigned short*)qb, (const unsigned short*)kb,
      (const unsigned short*)vb, o);
  oln1_kernel<<<B_ * N_, 128, 0, stream>>>(o, x, Wo, bo, lg1, lb1, x2);
  ffn1_kernel<<<B_ * N_, 256, 0, stream>>>(x2, W1, b1, h);
  ffn2ln_kernel<<<B_ * N_, 128, 0, stream>>>(h, x2, W2, b2p, lg2, lb2, feats);
  gatherfc_kernel<<<B_ * S_, 256, 0, stream>>>(feats, xyz, fps_idx, Wfc, bfc,
                                               g2, bb2, m2, v2, out1);
}

// Round 4
// 466.388 us; speedup vs baseline: 6.6006x; 5.0546x over previous
//
#include <hip/hip_runtime.h>
#include <hip/hip_bf16.h>

#define B_    8
#define N_    2048
#define CIN_  64
#define D_    128
#define DFF_  512
#define DOUT_ 256
#define S_    512
#define H_    4
#define HD_   32
#define EPS_  1e-5f

typedef unsigned short u16;
typedef __attribute__((ext_vector_type(8))) short short8v;  // 8 bf16
typedef __attribute__((ext_vector_type(4))) float f32x4;

__device__ __forceinline__ u16 f2bu(float f) {
  __hip_bfloat16 h = __float2bfloat16(f);
  return *(u16*)&h;
}
__device__ __forceinline__ float bu2f(u16 u) {
  __hip_bfloat16 h = *(__hip_bfloat16*)&u;
  return __bfloat162float(h);
}

// ---------------------------------------------------------------------------
// Weight prep: fold BN1 into W_proj, 1/sqrt(hd) into Wq/bq, BN2 into
// scale/shift; convert all GEMM weights to bf16 (padded K where needed).
// ---------------------------------------------------------------------------
#define OW_QKV 0
#define OW_O   49152
#define OW_1   65536
#define OW_2   131072
#define OW_FC  196608
#define OW_CAT 237568
#define NW_TOT 249856

__global__ __launch_bounds__(256) void prep_kernel(
    const float* __restrict__ Wq, const float* __restrict__ bq,
    const float* __restrict__ Wk, const float* __restrict__ bk,
    const float* __restrict__ Wv, const float* __restrict__ bv,
    const float* __restrict__ Wo, const float* __restrict__ W1,
    const float* __restrict__ W2, const float* __restrict__ Wfc,
    const float* __restrict__ bfc, const float* __restrict__ Wp,
    const float* __restrict__ bp, const float* __restrict__ Wpos,
    const float* __restrict__ bpos, const float* __restrict__ g1,
    const float* __restrict__ be1, const float* __restrict__ m1,
    const float* __restrict__ v1, const float* __restrict__ g2,
    const float* __restrict__ bb2, const float* __restrict__ m2,
    const float* __restrict__ v2, u16* __restrict__ wb,
    float* __restrict__ fb) {
  const float SC = 0.1767766952966369f;  // 1/sqrt(32)
  int i = blockIdx.x * 256 + threadIdx.x;
  if (i < OW_O) {  // Wqkv [384][128]
    int n = i >> 7, k = i & 127;
    float v = (n < 128) ? Wq[i] * SC
                        : (n < 256) ? Wk[(n - 128) * 128 + k]
                                    : Wv[(n - 256) * 128 + k];
    wb[OW_QKV + i] = f2bu(v);
  } else if (i < OW_1) {
    wb[i] = f2bu(Wo[i - OW_O]);
  } else if (i < OW_2) {
    wb[i] = f2bu(W1[i - OW_1]);
  } else if (i < OW_FC) {
    wb[i] = f2bu(W2[i - OW_2]);
  } else if (i < OW_CAT) {  // Wfc [256][160] (pad 131->160)
    int j = i - OW_FC;
    int n = j / 160, c = j % 160;
    wb[i] = f2bu(c < 131 ? Wfc[n * 131 + c] : 0.f);
  } else if (i < NW_TOT) {  // Wcat [128][96]: BN1-scaled Wp | Wpos | 0
    int j = i - OW_CAT;
    int d = j / 96, c = j % 96;
    float v;
    if (c < 64) v = Wp[d * 64 + c] * (g1[d] * rsqrtf(v1[d] + EPS_));
    else if (c < 67) v = Wpos[d * 3 + (c - 64)];
    else v = 0.f;
    wb[i] = f2bu(v);
  } else if (i < NW_TOT + 384) {  // bqkv
    int n = i - NW_TOT;
    fb[n] = (n < 128) ? bq[n] * SC : (n < 256) ? bk[n - 128] : bv[n - 256];
  } else if (i < NW_TOT + 512) {  // bias_x
    int d = i - (NW_TOT + 384);
    float s1 = g1[d] * rsqrtf(v1[d] + EPS_);
    fb[384 + d] = (bp[d] - m1[d]) * s1 + be1[d] + bpos[d];
  } else if (i < NW_TOT + 768) {  // fc_scale
    int n = i - (NW_TOT + 512);
    fb[512 + n] = g2[n] * rsqrtf(v2[n] + EPS_);
  } else if (i < NW_TOT + 1024) {  // fc_shift
    int n = i - (NW_TOT + 768);
    float s = g2[n] * rsqrtf(v2[n] + EPS_);
    fb[768 + n] = bfc[n] * s + bb2[n] - m2[n] * s;
  }
}

// ---------------------------------------------------------------------------
// FPS, latency-optimized: 4 waves, 8 contiguous pts/lane. Per-wave argmax via
// DPP max chain + ballot (exact first-occurrence). Cross-wave combine via u64
// keys (bits(M)<<32 | ~p) in double-buffered LDS, ONE barrier per step.
// Arithmetic exactly replicates numpy f32 (no FMA, (dx2+dy2)+dz2 order).
// ---------------------------------------------------------------------------
template <int CTRL, int RM>
__device__ __forceinline__ float dppmax(float v) {
  int m = __builtin_amdgcn_update_dpp(__float_as_int(v), __float_as_int(v),
                                      CTRL, RM, 0xF, true);
  return fmaxf(v, __int_as_float(m));
}

__global__ __launch_bounds__(256) void fps_kernel(const float* __restrict__ xyz,
                                                  int* __restrict__ idx_out,
                                                  float* __restrict__ out0) {
  const int b = blockIdx.x, t = threadIdx.x, w = t >> 6, lane = t & 63;
  const float* xb = xyz + (size_t)b * 3 * N_;
  __shared__ float xs[3 * N_];
  __shared__ unsigned long long keys[2][4];
  for (int i = t; i < 3 * N_; i += 256) xs[i] = xb[i];
  __syncthreads();
  const int base = w * 512 + lane * 8;
  float px[8], py[8], pz[8], dist[8];
#pragma unroll
  for (int j = 0; j < 8; j++) {
    px[j] = xs[base + j];
    py[j] = xs[N_ + base + j];
    pz[j] = xs[2 * N_ + base + j];
    dist[j] = 1e10f;
  }
  int far = 0;
  float cx = xs[0], cy = xs[N_], cz = xs[2 * N_];
  for (int s = 0; s < S_; s++) {
    if (t == 0) {
      idx_out[b * S_ + s] = far;
      out0[(size_t)b * 3 * S_ + s] = cx;
      out0[(size_t)b * 3 * S_ + S_ + s] = cy;
      out0[(size_t)b * 3 * S_ + 2 * S_ + s] = cz;
    }
    float best = -1.0f;
    int bestp = 0;
#pragma unroll
    for (int j = 0; j < 8; j++) {
      float dx = __fsub_rn(px[j], cx);
      float dy = __fsub_rn(py[j], cy);
      float dz = __fsub_rn(pz[j], cz);
      float d = __fadd_rn(__fadd_rn(__fmul_rn(dx, dx), __fmul_rn(dy, dy)),
                          __fmul_rn(dz, dz));
      float nd = fminf(dist[j], d);
      dist[j] = nd;
      if (nd > best) { best = nd; bestp = base + j; }  // ascending j: first max
    }
    // wave-wide max (value only) via DPP; result lands in lane 63
    float m = best;
    m = dppmax<0x111, 0xF>(m);  // row_shr:1
    m = dppmax<0x112, 0xF>(m);  // row_shr:2
    m = dppmax<0x114, 0xF>(m);  // row_shr:4
    m = dppmax<0x118, 0xF>(m);  // row_shr:8
    m = dppmax<0x142, 0xA>(m);  // row_bcast:15
    m = dppmax<0x143, 0xC>(m);  // row_bcast:31
    float M = __shfl(m, 63);
    unsigned long long mask = __ballot(best == M);
    int wl = __ffsll(mask) - 1;       // first lane = smallest point index
    int wp = __shfl(bestp, wl);       // that lane's first-occurrence index
    if (lane == 0)
      keys[s & 1][w] = ((unsigned long long)__float_as_uint(M) << 32) |
                       (unsigned)(0xFFFFFFFFu - (unsigned)wp);
    __syncthreads();
    unsigned long long k0 = keys[s & 1][0], k1 = keys[s & 1][1];
    unsigned long long k2 = keys[s & 1][2], k3 = keys[s & 1][3];
    unsigned long long ka = k0 > k1 ? k0 : k1;
    unsigned long long kb2 = k2 > k3 ? k2 : k3;
    unsigned long long kk = ka > kb2 ? ka : kb2;
    far = (int)(0xFFFFFFFFu - (unsigned)kk);
    cx = xs[far]; cy = xs[N_ + far]; cz = xs[2 * N_ + far];
  }
}

// ---------------------------------------------------------------------------
// Tiled bf16 MFMA GEMM template. C[128 x 128] tile per block, 4 waves,
// 16x16x32 MFMA. Frag contract (R3-verified): a[e]=A[l&15][8*(l>>4)+e],
// b[e]=W[l&15][8*(l>>4)+e] (W row-major [N][K]), d[i]=C[4*(l>>4)+i][l&15].
// ASTAGE: 0 = row-major bf16 A[M][K]; 1 = xfeat (channel-major f32 points|xyz,
//         zero pad to 96); 2 = gather rows of feats via fps_idx (+xyz, pad 160)
// EPI: 0 bias->bf16 [M][128]; 1 qkv scatter; 2 bias+relu->bf16 [M][512];
//      3 bias+residual+LayerNorm->bf16 [M][128]; 4 scale/shift/relu->f32 out1
// ---------------------------------------------------------------------------
template <int K, int KC, int ASTAGE, int EPI>
__global__ __launch_bounds__(256) void gemm_k(
    const u16* __restrict__ A, const u16* __restrict__ W,
    const float* __restrict__ srcf0, const float* __restrict__ srcf1,
    const int* __restrict__ fidx, const float* __restrict__ p0,
    const float* __restrict__ p1, const float* __restrict__ p2,
    const u16* __restrict__ resid, u16* __restrict__ outb,
    float* __restrict__ outf, int ntn) {
  constexpr int KP = KC + 8;
  __shared__ __align__(16) u16 As[128][KP];
  __shared__ __align__(16) u16 Ws[128][KP];
  const int mt = blockIdx.x / ntn, nt = blockIdx.x % ntn;
  const int t = threadIdx.x, w = t >> 6, lane = t & 63;
  const int g = lane >> 4, lr = lane & 15;

  f32x4 acc[2][8];
#pragma unroll
  for (int qf = 0; qf < 2; qf++)
#pragma unroll
    for (int nf = 0; nf < 8; nf++) acc[qf][nf] = {0.f, 0.f, 0.f, 0.f};

  for (int kc = 0; kc < K / KC; kc++) {
    __syncthreads();
    // ---- stage W tile [128][KC]
    for (int i = t; i < 128 * (KC / 8); i += 256) {
      int row = i / (KC / 8), c8 = i % (KC / 8);
      *(short8v*)&Ws[row][c8 * 8] =
          *(const short8v*)(W + (size_t)(nt * 128 + row) * K + kc * KC + c8 * 8);
    }
    // ---- stage A tile [128][KC]
    if constexpr (ASTAGE == 0) {
      for (int i = t; i < 128 * (KC / 8); i += 256) {
        int row = i / (KC / 8), c8 = i % (KC / 8);
        *(short8v*)&As[row][c8 * 8] =
            *(const short8v*)(A + (size_t)(mt * 128 + row) * K + kc * KC + c8 * 8);
      }
    } else if constexpr (ASTAGE == 1) {
      // tokens mt*128.. all within batch bb; cols: 64 points ch, 3 xyz, pad
      int bb = (mt * 128) >> 11, n0 = (mt * 128) & (N_ - 1);
      for (int i = t; i < 96 * 128; i += 256) {
        int c = i >> 7, n = i & 127;  // consecutive lanes -> consecutive n
        float v;
        if (c < 64) v = srcf0[((size_t)bb * CIN_ + c) * N_ + n0 + n];
        else if (c < 67) v = srcf1[((size_t)bb * 3 + (c - 64)) * N_ + n0 + n];
        else v = 0.f;
        As[n][c] = f2bu(v);
      }
    } else {  // ASTAGE == 2: gather feats rows by fps idx, + xyz, pad to 160
      int bb = (mt * 128) >> 9, s0 = (mt * 128) & (S_ - 1);
      for (int i = t; i < 128 * 20; i += 256) {
        int row = i / 20, c8 = i % 20;
        int id = fidx[bb * S_ + s0 + row];
        short8v val;
        if (c8 < 16) {
          val = *(const short8v*)(A + ((size_t)bb * N_ + id) * D_ + c8 * 8);
        } else if (c8 == 16) {
          val = short8v{0, 0, 0, 0, 0, 0, 0, 0};
          val[0] = (short)f2bu(srcf1[((size_t)bb * 3 + 0) * N_ + id]);
          val[1] = (short)f2bu(srcf1[((size_t)bb * 3 + 1) * N_ + id]);
          val[2] = (short)f2bu(srcf1[((size_t)bb * 3 + 2) * N_ + id]);
        } else {
          val = short8v{0, 0, 0, 0, 0, 0, 0, 0};
        }
        *(short8v*)&As[row][c8 * 8] = val;
      }
    }
    __syncthreads();
    // ---- MFMA over this K chunk
#pragma unroll
    for (int ks = 0; ks < KC / 32; ks++) {
      short8v a0 = *(const short8v*)&As[w * 32 + lr][ks * 32 + 8 * g];
      short8v a1 = *(const short8v*)&As[w * 32 + 16 + lr][ks * 32 + 8 * g];
#pragma unroll
      for (int nf = 0; nf < 8; nf++) {
        short8v bb = *(const short8v*)&Ws[nf * 16 + lr][ks * 32 + 8 * g];
        acc[0][nf] = __builtin_amdgcn_mfma_f32_16x16x32_bf16(a0, bb, acc[0][nf], 0, 0, 0);
        acc[1][nf] = __builtin_amdgcn_mfma_f32_16x16x32_bf16(a1, bb, acc[1][nf], 0, 0, 0);
      }
    }
  }

  // ---- epilogue
  if constexpr (EPI == 3) {  // bias + residual + LayerNorm (requires ntn==1)
#pragma unroll
    for (int qf = 0; qf < 2; qf++) {
#pragma unroll
      for (int i = 0; i < 4; i++) {
        int m = mt * 128 + w * 32 + qf * 16 + 4 * g + i;
        float v[8], sm = 0.f, sq = 0.f;
#pragma unroll
        for (int nf = 0; nf < 8; nf++) {
          int n = nf * 16 + lr;
          float x = acc[qf][nf][i] + p0[n] + bu2f(resid[(size_t)m * D_ + n]);
          v[nf] = x;
          sm += x;
          sq += x * x;
        }
#pragma unroll
        for (int msk = 1; msk < 16; msk <<= 1) {
          sm += __shfl_xor(sm, msk);
          sq += __shfl_xor(sq, msk);
        }
        float mu = sm * (1.f / 128.f);
        float var = sq * (1.f / 128.f) - mu * mu;
        float rs = rsqrtf(var + EPS_);
#pragma unroll
        for (int nf = 0; nf < 8; nf++) {
          int n = nf * 16 + lr;
          outb[(size_t)m * D_ + n] = f2bu((v[nf] - mu) * rs * p1[n] + p2[n]);
        }
      }
    }
  } else {
#pragma unroll
    for (int qf = 0; qf < 2; qf++)
#pragma unroll
      for (int nf = 0; nf < 8; nf++)
#pragma unroll
        for (int i = 0; i < 4; i++) {
          int m = mt * 128 + w * 32 + qf * 16 + 4 * g + i;
          int nl = nf * 16 + lr;
          int n = nt * 128 + nl;
          float vv = acc[qf][nf][i];
          if constexpr (EPI == 0) {
            outb[(size_t)m * D_ + nl] = f2bu(vv + p0[n]);
          } else if constexpr (EPI == 1) {
            vv += p0[n];
            int which = n >> 7, h = (n >> 5) & 3, c = n & 31;
            int bb = m >> 11, tok = m & (N_ - 1);
            outb[(size_t)which * 2097152 +
                 (((size_t)bb * H_ + h) * N_ + tok) * HD_ + c] = f2bu(vv);
          } else if constexpr (EPI == 2) {
            outb[(size_t)m * DFF_ + n] = f2bu(fmaxf(vv + p0[n], 0.f));
          } else {  // EPI == 4
            float r = fmaxf(vv * p1[n] + p2[n], 0.f);
            outf[((size_t)(m >> 9) * DOUT_ + n) * S_ + (m & (S_ - 1))] = r;
          }
        }
  }
}

// ---------------------------------------------------------------------------
// Flash attention with bf16 MFMA (unchanged from R3 except bf16 output).
// ---------------------------------------------------------------------------
__global__ __launch_bounds__(256) void attn_mfma_kernel(
    const u16* __restrict__ qg, const u16* __restrict__ kg,
    const u16* __restrict__ vg, u16* __restrict__ o) {
  const int bid = blockIdx.x;
  const int qt = bid & 15;
  const int bh = bid >> 4;
  const int b = bh >> 2, h = bh & 3;
  const int t = threadIdx.x;
  const int w = t >> 6, lane = t & 63, g = lane >> 4, lr = lane & 15;

  __shared__ __align__(16) u16 ks[64][40];
  __shared__ __align__(16) u16 vt[32][72];
  __shared__ __align__(16) u16 ps[4][32][72];

  const int qbase = qt * 128 + w * 32;
  const u16* qrow = qg + ((size_t)bh * N_ + qbase) * HD_;
  short8v aq[2];
#pragma unroll
  for (int qf = 0; qf < 2; qf++)
    aq[qf] = *(const short8v*)(qrow + (qf * 16 + lr) * HD_ + 8 * g);

  const u16* kb = kg + (size_t)bh * N_ * HD_;
  const u16* vb = vg + (size_t)bh * N_ * HD_;

  const f32x4 fzero = {0.f, 0.f, 0.f, 0.f};
  float mrun[2][4], lrun[2][4];
  f32x4 acco[2][2];
#pragma unroll
  for (int qf = 0; qf < 2; qf++) {
#pragma unroll
    for (int i = 0; i < 4; i++) { mrun[qf][i] = -INFINITY; lrun[qf][i] = 0.f; }
    acco[qf][0] = fzero;
    acco[qf][1] = fzero;
  }

  const int srow = t >> 2, scol = (t & 3) * 8;

  for (int ch = 0; ch < 32; ch++) {
    __syncthreads();
    short8v kvv = *(const short8v*)(kb + (size_t)(ch * 64 + srow) * HD_ + scol);
    short8v vvv = *(const short8v*)(vb + (size_t)(ch * 64 + srow) * HD_ + scol);
    *(short8v*)(&ks[srow][scol]) = kvv;
#pragma unroll
    for (int e = 0; e < 8; e++) vt[scol + e][srow] = (u16)vvv[e];
    __syncthreads();

    f32x4 s[2][4];
#pragma unroll
    for (int qf = 0; qf < 2; qf++)
#pragma unroll
      for (int kt = 0; kt < 4; kt++) {
        short8v bk = *(const short8v*)(&ks[kt * 16 + lr][8 * g]);
        s[qf][kt] =
            __builtin_amdgcn_mfma_f32_16x16x32_bf16(aq[qf], bk, fzero, 0, 0, 0);
      }

#pragma unroll
    for (int qf = 0; qf < 2; qf++) {
#pragma unroll
      for (int i = 0; i < 4; i++) {
        float mx = fmaxf(fmaxf(s[qf][0][i], s[qf][1][i]),
                         fmaxf(s[qf][2][i], s[qf][3][i]));
#pragma unroll
        for (int m = 1; m < 16; m <<= 1) mx = fmaxf(mx, __shfl_xor(mx, m));
        float nm = fmaxf(mrun[qf][i], mx);
        float alpha = __expf(mrun[qf][i] - nm);
        mrun[qf][i] = nm;
        float psum = 0.f;
#pragma unroll
        for (int kt = 0; kt < 4; kt++) {
          float pv = __expf(s[qf][kt][i] - nm);
          psum += pv;
          ps[w][qf * 16 + 4 * g + i][kt * 16 + lr] = f2bu(pv);
        }
#pragma unroll
        for (int m = 1; m < 16; m <<= 1) psum += __shfl_xor(psum, m);
        lrun[qf][i] = lrun[qf][i] * alpha + psum;
        acco[qf][0][i] *= alpha;
        acco[qf][1][i] *= alpha;
      }
    }

#pragma unroll
    for (int qf = 0; qf < 2; qf++)
#pragma unroll
      for (int mc = 0; mc < 2; mc++) {
        short8v pa = *(const short8v*)(&ps[w][qf * 16 + lr][mc * 32 + 8 * g]);
#pragma unroll
        for (int dt = 0; dt < 2; dt++) {
          short8v bv = *(const short8v*)(&vt[dt * 16 + lr][mc * 32 + 8 * g]);
          acco[qf][dt] = __builtin_amdgcn_mfma_f32_16x16x32_bf16(
              pa, bv, acco[qf][dt], 0, 0, 0);
        }
      }
  }

#pragma unroll
  for (int qf = 0; qf < 2; qf++)
#pragma unroll
    for (int dt = 0; dt < 2; dt++)
#pragma unroll
      for (int i = 0; i < 4; i++) {
        int row = qbase + qf * 16 + 4 * g + i;
        o[((size_t)b * N_ + row) * D_ + h * HD_ + dt * 16 + lr] =
            f2bu(acco[qf][dt][i] / lrun[qf][i]);
      }
}

// ---------------------------------------------------------------------------
extern "C" void kernel_launch(void* const* d_in, const int* in_sizes, int n_in,
                              void* d_out, int out_size, void* d_ws, size_t ws_size,
                              hipStream_t stream) {
  const float* xyz    = (const float*)d_in[0];
  const float* points = (const float*)d_in[1];
  const float* Wp     = (const float*)d_in[2];
  const float* bp     = (const float*)d_in[3];
  const float* g1     = (const float*)d_in[4];
  const float* be1    = (const float*)d_in[5];
  const float* m1     = (const float*)d_in[6];
  const float* v1     = (const float*)d_in[7];
  const float* Wpos   = (const float*)d_in[8];
  const float* bpos   = (const float*)d_in[9];
  const float* Wq     = (const float*)d_in[10];
  const float* bq     = (const float*)d_in[11];
  const float* Wk     = (const float*)d_in[12];
  const float* bk     = (const float*)d_in[13];
  const float* Wv     = (const float*)d_in[14];
  const float* bv     = (const float*)d_in[15];
  const float* Wo     = (const float*)d_in[16];
  const float* bo     = (const float*)d_in[17];
  const float* lg1    = (const float*)d_in[18];
  const float* lb1    = (const float*)d_in[19];
  const float* W1     = (const float*)d_in[20];
  const float* b1     = (const float*)d_in[21];
  const float* W2     = (const float*)d_in[22];
  const float* b2p    = (const float*)d_in[23];
  const float* lg2    = (const float*)d_in[24];
  const float* lb2    = (const float*)d_in[25];
  const float* Wfc    = (const float*)d_in[26];
  const float* bfc    = (const float*)d_in[27];
  const float* g2     = (const float*)d_in[28];
  const float* bb2    = (const float*)d_in[29];
  const float* m2     = (const float*)d_in[30];
  const float* v2     = (const float*)d_in[31];

  float* out0 = (float*)d_out;               // [B,3,S]
  float* out1 = out0 + (size_t)B_ * 3 * S_;  // [B,Dout,S]

  char* ws = (char*)d_ws;
  int*   fps_idx = (int*)ws;                          // 16 KB
  u16*   wb      = (u16*)(ws + 16384);                // 249856 bf16
  float* fb      = (float*)(ws + 516096);             // 1024 f32
  const size_t MB = 1024 * 1024;
  u16* x     = (u16*)(ws + 1 * MB);    // [16384][128]
  u16* o     = (u16*)(ws + 5 * MB);    // [B,N,128]
  u16* x2    = (u16*)(ws + 9 * MB);    // [16384][128]
  u16* feats = (u16*)(ws + 13 * MB);   // [16384][128]
  u16* qb    = (u16*)(ws + 17 * MB);   // q|k|v, each [B,H,N,32]
  u16* h     = (u16*)(ws + 29 * MB);   // [16384][512]

  prep_kernel<<<980, 256, 0, stream>>>(Wq, bq, Wk, bk, Wv, bv, Wo, W1, W2, Wfc,
                                       bfc, Wp, bp, Wpos, bpos, g1, be1, m1, v1,
                                       g2, bb2, m2, v2, wb, fb);
  fps_kernel<<<B_, 256, 0, stream>>>(xyz, fps_idx, out0);

  // x = BN1(proj)+pos  (Wcat, bias_x)
  gemm_k<96, 96, 1, 0><<<128, 256, 0, stream>>>(
      nullptr, wb + OW_CAT, points, xyz, nullptr, fb + 384, nullptr, nullptr,
      nullptr, x, nullptr, 1);
  // qkv
  gemm_k<128, 128, 0, 1><<<384, 256, 0, stream>>>(
      x, wb + OW_QKV, nullptr, nullptr, nullptr, fb, nullptr, nullptr,
      nullptr, qb, nullptr, 3);
  attn_mfma_kernel<<<B_ * H_ * (N_ / 128), 256, 0, stream>>>(
      qb, qb + 2097152, qb + 2 * 2097152, o);
  // x2 = LN1(x + o@Wo^T + bo)
  gemm_k<128, 128, 0, 3><<<128, 256, 0, stream>>>(
      o, wb + OW_O, nullptr, nullptr, nullptr, bo, lg1, lb1, x, x2, nullptr, 1);
  // h = relu(x2@W1^T + b1)
  gemm_k<128, 128, 0, 2><<<512, 256, 0, stream>>>(
      x2, wb + OW_1, nullptr, nullptr, nullptr, b1, nullptr, nullptr,
      nullptr, h, nullptr, 4);
  // feats = LN2(x2 + h@W2^T + b2)
  gemm_k<512, 128, 0, 3><<<128, 256, 0, stream>>>(
      h, wb + OW_2, nullptr, nullptr, nullptr, b2p, lg2, lb2, x2, feats,
      nullptr, 1);
  // out1 = relu(BN2(gather(feats,xyz)@Wfc^T + bfc))
  gemm_k<160, 160, 2, 4><<<64, 256, 0, stream>>>(
      feats, wb + OW_FC, nullptr, xyz, fps_idx, nullptr, fb + 512, fb + 768,
      nullptr, nullptr, out1, 2);
}

// Round 5
// 367.152 us; speedup vs baseline: 8.3846x; 1.2703x over previous
//
#include <hip/hip_runtime.h>
#include <hip/hip_bf16.h>

#define B_    8
#define N_    2048
#define CIN_  64
#define D_    128
#define DFF_  512
#define DOUT_ 256
#define S_    512
#define H_    4
#define HD_   32
#define EPS_  1e-5f

typedef unsigned short u16;
typedef unsigned long long u64;
typedef __attribute__((ext_vector_type(8))) short short8v;  // 8 bf16
typedef __attribute__((ext_vector_type(4))) float f32x4;

__device__ __forceinline__ u16 f2bu(float f) {
  __hip_bfloat16 h = __float2bfloat16(f);
  return *(u16*)&h;
}
__device__ __forceinline__ float bu2f(u16 u) {
  __hip_bfloat16 h = *(__hip_bfloat16*)&u;
  return __bfloat162float(h);
}

// ---------------------------------------------------------------------------
// Weight prep: fold BN1 into W_proj, 1/sqrt(hd) into Wq/bq, BN2 into
// scale/shift; convert all GEMM weights to bf16 (padded K where needed).
// ---------------------------------------------------------------------------
#define OW_QKV 0
#define OW_O   49152
#define OW_1   65536
#define OW_2   131072
#define OW_FC  196608
#define OW_CAT 237568
#define NW_TOT 249856

__global__ __launch_bounds__(256) void prep_kernel(
    const float* __restrict__ Wq, const float* __restrict__ bq,
    const float* __restrict__ Wk, const float* __restrict__ bk,
    const float* __restrict__ Wv, const float* __restrict__ bv,
    const float* __restrict__ Wo, const float* __restrict__ W1,
    const float* __restrict__ W2, const float* __restrict__ Wfc,
    const float* __restrict__ bfc, const float* __restrict__ Wp,
    const float* __restrict__ bp, const float* __restrict__ Wpos,
    const float* __restrict__ bpos, const float* __restrict__ g1,
    const float* __restrict__ be1, const float* __restrict__ m1,
    const float* __restrict__ v1, const float* __restrict__ g2,
    const float* __restrict__ bb2, const float* __restrict__ m2,
    const float* __restrict__ v2, u16* __restrict__ wb,
    float* __restrict__ fb) {
  const float SC = 0.1767766952966369f;  // 1/sqrt(32)
  int i = blockIdx.x * 256 + threadIdx.x;
  if (i < OW_O) {  // Wqkv [384][128]
    int n = i >> 7, k = i & 127;
    float v = (n < 128) ? Wq[i] * SC
                        : (n < 256) ? Wk[(n - 128) * 128 + k]
                                    : Wv[(n - 256) * 128 + k];
    wb[OW_QKV + i] = f2bu(v);
  } else if (i < OW_1) {
    wb[i] = f2bu(Wo[i - OW_O]);
  } else if (i < OW_2) {
    wb[i] = f2bu(W1[i - OW_1]);
  } else if (i < OW_FC) {
    wb[i] = f2bu(W2[i - OW_2]);
  } else if (i < OW_CAT) {  // Wfc [256][160] (pad 131->160)
    int j = i - OW_FC;
    int n = j / 160, c = j % 160;
    wb[i] = f2bu(c < 131 ? Wfc[n * 131 + c] : 0.f);
  } else if (i < NW_TOT) {  // Wcat [128][96]: BN1-scaled Wp | Wpos | 0
    int j = i - OW_CAT;
    int d = j / 96, c = j % 96;
    float v;
    if (c < 64) v = Wp[d * 64 + c] * (g1[d] * rsqrtf(v1[d] + EPS_));
    else if (c < 67) v = Wpos[d * 3 + (c - 64)];
    else v = 0.f;
    wb[i] = f2bu(v);
  } else if (i < NW_TOT + 384) {  // bqkv
    int n = i - NW_TOT;
    fb[n] = (n < 128) ? bq[n] * SC : (n < 256) ? bk[n - 128] : bv[n - 256];
  } else if (i < NW_TOT + 512) {  // bias_x
    int d = i - (NW_TOT + 384);
    float s1 = g1[d] * rsqrtf(v1[d] + EPS_);
    fb[384 + d] = (bp[d] - m1[d]) * s1 + be1[d] + bpos[d];
  } else if (i < NW_TOT + 768) {  // fc_scale
    int n = i - (NW_TOT + 512);
    fb[512 + n] = g2[n] * rsqrtf(v2[n] + EPS_);
  } else if (i < NW_TOT + 1024) {  // fc_shift
    int n = i - (NW_TOT + 768);
    float s = g2[n] * rsqrtf(v2[n] + EPS_);
    fb[768 + n] = bfc[n] * s + bb2[n] - m2[n] * s;
  }
}

// ---------------------------------------------------------------------------
// FPS slice: runs steps [s0,s1) of farthest-point sampling for one batch,
// as 8 extra blocks hosted inside the pipeline kernels (state in d_ws).
// Arithmetic exactly replicates numpy f32 (no FMA, (dx2+dy2)+dz2 order);
// argmax = first occurrence. 256 threads, 8 pts/lane. Value-reduce via DPP,
// broadcasts via v_readlane (fast SALU) instead of ds_bpermute.
// LDS need: 3*N*4 + 64 = 24640 B, carved from host kernel's smem union.
// ---------------------------------------------------------------------------
#define FPS_SMEM 24704

template <int CTRL, int RM>
__device__ __forceinline__ float dppmax(float v) {
  int m = __builtin_amdgcn_update_dpp(__float_as_int(v), __float_as_int(v),
                                      CTRL, RM, 0xF, true);
  return fmaxf(v, __int_as_float(m));
}

__device__ __forceinline__ void fps_slice(
    char* smem, int b, const float* __restrict__ xyz,
    float* __restrict__ dist_ws, int* __restrict__ far_ws,
    int* __restrict__ idx_out, float* __restrict__ out0, int s0, int s1) {
  float* xs = (float*)smem;
  u64* keys = (u64*)(smem + 3 * N_ * 4);  // [2][4]
  const int t = threadIdx.x, w = t >> 6, lane = t & 63;
  const float* xb = xyz + (size_t)b * 3 * N_;
  for (int i = t; i < 3 * N_; i += 256) xs[i] = xb[i];
  const int base = w * 512 + lane * 8;
  float* dw = dist_ws + b * N_;
  float dist[8];
  if (s0 == 0) {
#pragma unroll
    for (int j = 0; j < 8; j++) dist[j] = 1e10f;
  } else {
#pragma unroll
    for (int j = 0; j < 8; j++) dist[j] = dw[base + j];
  }
  int far = (s0 == 0) ? 0 : far_ws[b];
  __syncthreads();
  float px[8], py[8], pz[8];
#pragma unroll
  for (int j = 0; j < 8; j++) {
    px[j] = xs[base + j];
    py[j] = xs[N_ + base + j];
    pz[j] = xs[2 * N_ + base + j];
  }
  float cx = xs[far], cy = xs[N_ + far], cz = xs[2 * N_ + far];
  for (int s = s0; s < s1; s++) {
    if (t == 0) {
      idx_out[b * S_ + s] = far;
      out0[(size_t)b * 3 * S_ + s] = cx;
      out0[(size_t)b * 3 * S_ + S_ + s] = cy;
      out0[(size_t)b * 3 * S_ + 2 * S_ + s] = cz;
    }
    float best = -1.0f;
    int bestp = 0;
#pragma unroll
    for (int j = 0; j < 8; j++) {
      float dx = __fsub_rn(px[j], cx);
      float dy = __fsub_rn(py[j], cy);
      float dz = __fsub_rn(pz[j], cz);
      float d = __fadd_rn(__fadd_rn(__fmul_rn(dx, dx), __fmul_rn(dy, dy)),
                          __fmul_rn(dz, dz));
      float nd = fminf(dist[j], d);
      dist[j] = nd;
      if (nd > best) { best = nd; bestp = base + j; }  // ascending j: first max
    }
    // wave-wide max (value only) via DPP; lane 63 holds the wave max
    float m = best;
    m = dppmax<0x111, 0xF>(m);  // row_shr:1
    m = dppmax<0x112, 0xF>(m);  // row_shr:2
    m = dppmax<0x114, 0xF>(m);  // row_shr:4
    m = dppmax<0x118, 0xF>(m);  // row_shr:8
    m = dppmax<0x142, 0xA>(m);  // row_bcast:15
    m = dppmax<0x143, 0xC>(m);  // row_bcast:31
    float M = __int_as_float(__builtin_amdgcn_readlane(__float_as_int(m), 63));
    u64 mask = __ballot(best == M);
    int wl = __ffsll((long long)mask) - 1;  // first lane = smallest point idx
    int wp = __builtin_amdgcn_readlane(bestp, wl);
    if (lane == 0)
      keys[(s & 1) * 4 + w] = ((u64)__float_as_uint(M) << 32) |
                              (unsigned)(0xFFFFFFFFu - (unsigned)wp);
    __syncthreads();
    const u64* kp = keys + (s & 1) * 4;
    u64 k0 = kp[0], k1 = kp[1], k2 = kp[2], k3 = kp[3];
    u64 ka = k0 > k1 ? k0 : k1;
    u64 kb2 = k2 > k3 ? k2 : k3;
    u64 kk = ka > kb2 ? ka : kb2;
    far = (int)(0xFFFFFFFFu - (unsigned)kk);
    cx = xs[far];
    cy = xs[N_ + far];
    cz = xs[2 * N_ + far];
  }
#pragma unroll
  for (int j = 0; j < 8; j++) dw[base + j] = dist[j];
  if (t == 0) far_ws[b] = far;
}

// ---------------------------------------------------------------------------
// Tiled bf16 MFMA GEMM template (+ optional FPS co-blocks at blockIdx < fpsnb).
// C[128 x 128] tile per block, 4 waves, 16x16x32 MFMA.
// Frag contract (R3-verified): a[e]=A[l&15][8*(l>>4)+e],
// b[e]=W[l&15][8*(l>>4)+e] (W row-major [N][K]), d[i]=C[4*(l>>4)+i][l&15].
// ASTAGE: 0 row-major bf16 A[M][K]; 1 xfeat (channel-major f32, pad 96);
//         2 gather feats rows via fps_idx (+xyz, pad 160)
// EPI: 0 bias->bf16; 1 qkv scatter; 2 bias+relu->bf16 [M][512];
//      3 bias+residual+LayerNorm->bf16; 4 scale/shift/relu->f32 out1
// ---------------------------------------------------------------------------
template <int K, int KC, int ASTAGE, int EPI>
__global__ __launch_bounds__(256) void gemm_k(
    const u16* __restrict__ A, const u16* __restrict__ W,
    const float* __restrict__ srcf0, const float* __restrict__ srcf1,
    const int* __restrict__ fidx, const float* __restrict__ p0,
    const float* __restrict__ p1, const float* __restrict__ p2,
    const u16* __restrict__ resid, u16* __restrict__ outb,
    float* __restrict__ outf, int ntn, int fpsnb, int s0, int s1,
    const float* fxyz, float* fdist, int* ffar, int* fidxo, float* fout0) {
  constexpr int KP = KC + 8;
  constexpr int GEMM_SMEM = 2 * 128 * KP * 2;
  constexpr int SMEM = GEMM_SMEM > FPS_SMEM ? GEMM_SMEM : FPS_SMEM;
  __shared__ __align__(16) char smem[SMEM];
  if ((int)blockIdx.x < fpsnb) {
    fps_slice(smem, blockIdx.x, fxyz, fdist, ffar, fidxo, fout0, s0, s1);
    return;
  }
  u16 (*As)[KP] = (u16 (*)[KP])smem;
  u16 (*Ws)[KP] = (u16 (*)[KP])(smem + 128 * KP * 2);
  const int bid = blockIdx.x - fpsnb;
  const int mt = bid / ntn, nt = bid % ntn;
  const int t = threadIdx.x, w = t >> 6, lane = t & 63;
  const int g = lane >> 4, lr = lane & 15;

  f32x4 acc[2][8];
#pragma unroll
  for (int qf = 0; qf < 2; qf++)
#pragma unroll
    for (int nf = 0; nf < 8; nf++) acc[qf][nf] = {0.f, 0.f, 0.f, 0.f};

  for (int kc = 0; kc < K / KC; kc++) {
    __syncthreads();
    // ---- stage W tile [128][KC]
    for (int i = t; i < 128 * (KC / 8); i += 256) {
      int row = i / (KC / 8), c8 = i % (KC / 8);
      *(short8v*)&Ws[row][c8 * 8] =
          *(const short8v*)(W + (size_t)(nt * 128 + row) * K + kc * KC + c8 * 8);
    }
    // ---- stage A tile [128][KC]
    if constexpr (ASTAGE == 0) {
      for (int i = t; i < 128 * (KC / 8); i += 256) {
        int row = i / (KC / 8), c8 = i % (KC / 8);
        *(short8v*)&As[row][c8 * 8] =
            *(const short8v*)(A + (size_t)(mt * 128 + row) * K + kc * KC + c8 * 8);
      }
    } else if constexpr (ASTAGE == 1) {
      int bb = (mt * 128) >> 11, n0 = (mt * 128) & (N_ - 1);
      for (int i = t; i < 96 * 128; i += 256) {
        int c = i >> 7, n = i & 127;
        float v;
        if (c < 64) v = srcf0[((size_t)bb * CIN_ + c) * N_ + n0 + n];
        else if (c < 67) v = srcf1[((size_t)bb * 3 + (c - 64)) * N_ + n0 + n];
        else v = 0.f;
        As[n][c] = f2bu(v);
      }
    } else {  // ASTAGE == 2
      int bb = (mt * 128) >> 9, sq0 = (mt * 128) & (S_ - 1);
      for (int i = t; i < 128 * 20; i += 256) {
        int row = i / 20, c8 = i % 20;
        int id = fidx[bb * S_ + sq0 + row];
        short8v val;
        if (c8 < 16) {
          val = *(const short8v*)(A + ((size_t)bb * N_ + id) * D_ + c8 * 8);
        } else if (c8 == 16) {
          val = short8v{0, 0, 0, 0, 0, 0, 0, 0};
          val[0] = (short)f2bu(srcf1[((size_t)bb * 3 + 0) * N_ + id]);
          val[1] = (short)f2bu(srcf1[((size_t)bb * 3 + 1) * N_ + id]);
          val[2] = (short)f2bu(srcf1[((size_t)bb * 3 + 2) * N_ + id]);
        } else {
          val = short8v{0, 0, 0, 0, 0, 0, 0, 0};
        }
        *(short8v*)&As[row][c8 * 8] = val;
      }
    }
    __syncthreads();
    // ---- MFMA over this K chunk
#pragma unroll
    for (int ks = 0; ks < KC / 32; ks++) {
      short8v a0 = *(const short8v*)&As[w * 32 + lr][ks * 32 + 8 * g];
      short8v a1 = *(const short8v*)&As[w * 32 + 16 + lr][ks * 32 + 8 * g];
#pragma unroll
      for (int nf = 0; nf < 8; nf++) {
        short8v bb = *(const short8v*)&Ws[nf * 16 + lr][ks * 32 + 8 * g];
        acc[0][nf] = __builtin_amdgcn_mfma_f32_16x16x32_bf16(a0, bb, acc[0][nf], 0, 0, 0);
        acc[1][nf] = __builtin_amdgcn_mfma_f32_16x16x32_bf16(a1, bb, acc[1][nf], 0, 0, 0);
      }
    }
  }

  // ---- epilogue
  if constexpr (EPI == 3) {  // bias + residual + LayerNorm (ntn==1)
#pragma unroll
    for (int qf = 0; qf < 2; qf++) {
#pragma unroll
      for (int i = 0; i < 4; i++) {
        int m = mt * 128 + w * 32 + qf * 16 + 4 * g + i;
        float v[8], sm = 0.f, sq = 0.f;
#pragma unroll
        for (int nf = 0; nf < 8; nf++) {
          int n = nf * 16 + lr;
          float x = acc[qf][nf][i] + p0[n] + bu2f(resid[(size_t)m * D_ + n]);
          v[nf] = x;
          sm += x;
          sq += x * x;
        }
#pragma unroll
        for (int msk = 1; msk < 16; msk <<= 1) {
          sm += __shfl_xor(sm, msk);
          sq += __shfl_xor(sq, msk);
        }
        float mu = sm * (1.f / 128.f);
        float var = sq * (1.f / 128.f) - mu * mu;
        float rs = rsqrtf(var + EPS_);
#pragma unroll
        for (int nf = 0; nf < 8; nf++) {
          int n = nf * 16 + lr;
          outb[(size_t)m * D_ + n] = f2bu((v[nf] - mu) * rs * p1[n] + p2[n]);
        }
      }
    }
  } else {
#pragma unroll
    for (int qf = 0; qf < 2; qf++)
#pragma unroll
      for (int nf = 0; nf < 8; nf++)
#pragma unroll
        for (int i = 0; i < 4; i++) {
          int m = mt * 128 + w * 32 + qf * 16 + 4 * g + i;
          int nl = nf * 16 + lr;
          int n = nt * 128 + nl;
          float vv = acc[qf][nf][i];
          if constexpr (EPI == 0) {
            outb[(size_t)m * D_ + nl] = f2bu(vv + p0[n]);
          } else if constexpr (EPI == 1) {
            vv += p0[n];
            int which = n >> 7, h = (n >> 5) & 3, c = n & 31;
            int bb = m >> 11, tok = m & (N_ - 1);
            outb[(size_t)which * 2097152 +
                 (((size_t)bb * H_ + h) * N_ + tok) * HD_ + c] = f2bu(vv);
          } else if constexpr (EPI == 2) {
            outb[(size_t)m * DFF_ + n] = f2bu(fmaxf(vv + p0[n], 0.f));
          } else {  // EPI == 4
            float r = fmaxf(vv * p1[n] + p2[n], 0.f);
            outf[((size_t)(m >> 9) * DOUT_ + n) * S_ + (m & (S_ - 1))] = r;
          }
        }
  }
}

// ---------------------------------------------------------------------------
// Flash attention with bf16 MFMA (+ FPS co-blocks at blockIdx < fpsnb).
// ---------------------------------------------------------------------------
__global__ __launch_bounds__(256) void attn_mfma_kernel(
    const u16* __restrict__ qg, const u16* __restrict__ kg,
    const u16* __restrict__ vg, u16* __restrict__ o, int fpsnb, int s0, int s1,
    const float* fxyz, float* fdist, int* ffar, int* fidxo, float* fout0) {
  constexpr int ATTN_SMEM = 64 * 40 * 2 + 32 * 72 * 2 + 4 * 32 * 72 * 2;
  constexpr int SMEM = ATTN_SMEM > FPS_SMEM ? ATTN_SMEM : FPS_SMEM;
  __shared__ __align__(16) char smem[SMEM];
  if ((int)blockIdx.x < fpsnb) {
    fps_slice(smem, blockIdx.x, fxyz, fdist, ffar, fidxo, fout0, s0, s1);
    return;
  }
  u16 (*ks)[40] = (u16 (*)[40])smem;                          // 5120 B
  u16 (*vt)[72] = (u16 (*)[72])(smem + 5120);                 // 4608 B
  u16 (*ps)[32][72] = (u16 (*)[32][72])(smem + 5120 + 4608);  // 18432 B

  const int bid = blockIdx.x - fpsnb;
  const int qt = bid & 15;
  const int bh = bid >> 4;
  const int b = bh >> 2, h = bh & 3;
  const int t = threadIdx.x;
  const int w = t >> 6, lane = t & 63, g = lane >> 4, lr = lane & 15;

  const int qbase = qt * 128 + w * 32;
  const u16* qrow = qg + ((size_t)bh * N_ + qbase) * HD_;
  short8v aq[2];
#pragma unroll
  for (int qf = 0; qf < 2; qf++)
    aq[qf] = *(const short8v*)(qrow + (qf * 16 + lr) * HD_ + 8 * g);

  const u16* kb = kg + (size_t)bh * N_ * HD_;
  const u16* vb = vg + (size_t)bh * N_ * HD_;

  const f32x4 fzero = {0.f, 0.f, 0.f, 0.f};
  float mrun[2][4], lrun[2][4];
  f32x4 acco[2][2];
#pragma unroll
  for (int qf = 0; qf < 2; qf++) {
#pragma unroll
    for (int i = 0; i < 4; i++) { mrun[qf][i] = -INFINITY; lrun[qf][i] = 0.f; }
    acco[qf][0] = fzero;
    acco[qf][1] = fzero;
  }

  const int srow = t >> 2, scol = (t & 3) * 8;

  for (int ch = 0; ch < 32; ch++) {
    __syncthreads();
    short8v kvv = *(const short8v*)(kb + (size_t)(ch * 64 + srow) * HD_ + scol);
    short8v vvv = *(const short8v*)(vb + (size_t)(ch * 64 + srow) * HD_ + scol);
    *(short8v*)(&ks[srow][scol]) = kvv;
#pragma unroll
    for (int e = 0; e < 8; e++) vt[scol + e][srow] = (u16)vvv[e];
    __syncthreads();

    f32x4 s[2][4];
#pragma unroll
    for (int qf = 0; qf < 2; qf++)
#pragma unroll
      for (int kt = 0; kt < 4; kt++) {
        short8v bk = *(const short8v*)(&ks[kt * 16 + lr][8 * g]);
        s[qf][kt] =
            __builtin_amdgcn_mfma_f32_16x16x32_bf16(aq[qf], bk, fzero, 0, 0, 0);
      }

#pragma unroll
    for (int qf = 0; qf < 2; qf++) {
#pragma unroll
      for (int i = 0; i < 4; i++) {
        float mx = fmaxf(fmaxf(s[qf][0][i], s[qf][1][i]),
                         fmaxf(s[qf][2][i], s[qf][3][i]));
#pragma unroll
        for (int m = 1; m < 16; m <<= 1) mx = fmaxf(mx, __shfl_xor(mx, m));
        float nm = fmaxf(mrun[qf][i], mx);
        float alpha = __expf(mrun[qf][i] - nm);
        mrun[qf][i] = nm;
        float psum = 0.f;
#pragma unroll
        for (int kt = 0; kt < 4; kt++) {
          float pv = __expf(s[qf][kt][i] - nm);
          psum += pv;
          ps[w][qf * 16 + 4 * g + i][kt * 16 + lr] = f2bu(pv);
        }
#pragma unroll
        for (int m = 1; m < 16; m <<= 1) psum += __shfl_xor(psum, m);
        lrun[qf][i] = lrun[qf][i] * alpha + psum;
        acco[qf][0][i] *= alpha;
        acco[qf][1][i] *= alpha;
      }
    }

#pragma unroll
    for (int qf = 0; qf < 2; qf++)
#pragma unroll
      for (int mc = 0; mc < 2; mc++) {
        short8v pa = *(const short8v*)(&ps[w][qf * 16 + lr][mc * 32 + 8 * g]);
#pragma unroll
        for (int dt = 0; dt < 2; dt++) {
          short8v bv = *(const short8v*)(&vt[dt * 16 + lr][mc * 32 + 8 * g]);
          acco[qf][dt] = __builtin_amdgcn_mfma_f32_16x16x32_bf16(
              pa, bv, acco[qf][dt], 0, 0, 0);
        }
      }
  }

#pragma unroll
  for (int qf = 0; qf < 2; qf++)
#pragma unroll
    for (int dt = 0; dt < 2; dt++)
#pragma unroll
      for (int i = 0; i < 4; i++) {
        int row = qbase + qf * 16 + 4 * g + i;
        o[((size_t)b * N_ + row) * D_ + h * HD_ + dt * 16 + lr] =
            f2bu(acco[qf][dt][i] / lrun[qf][i]);
      }
}

// ---------------------------------------------------------------------------
extern "C" void kernel_launch(void* const* d_in, const int* in_sizes, int n_in,
                              void* d_out, int out_size, void* d_ws, size_t ws_size,
                              hipStream_t stream) {
  const float* xyz    = (const float*)d_in[0];
  const float* points = (const float*)d_in[1];
  const float* Wp     = (const float*)d_in[2];
  const float* bp     = (const float*)d_in[3];
  const float* g1     = (const float*)d_in[4];
  const float* be1    = (const float*)d_in[5];
  const float* m1     = (const float*)d_in[6];
  const float* v1     = (const float*)d_in[7];
  const float* Wpos   = (const float*)d_in[8];
  const float* bpos   = (const float*)d_in[9];
  const float* Wq     = (const float*)d_in[10];
  const float* bq     = (const float*)d_in[11];
  const float* Wk     = (const float*)d_in[12];
  const float* bk     = (const float*)d_in[13];
  const float* Wv     = (const float*)d_in[14];
  const float* bv     = (const float*)d_in[15];
  const float* Wo     = (const float*)d_in[16];
  const float* bo     = (const float*)d_in[17];
  const float* lg1    = (const float*)d_in[18];
  const float* lb1    = (const float*)d_in[19];
  const float* W1     = (const float*)d_in[20];
  const float* b1     = (const float*)d_in[21];
  const float* W2     = (const float*)d_in[22];
  const float* b2p    = (const float*)d_in[23];
  const float* lg2    = (const float*)d_in[24];
  const float* lb2    = (const float*)d_in[25];
  const float* Wfc    = (const float*)d_in[26];
  const float* bfc    = (const float*)d_in[27];
  const float* g2     = (const float*)d_in[28];
  const float* bb2    = (const float*)d_in[29];
  const float* m2     = (const float*)d_in[30];
  const float* v2     = (const float*)d_in[31];

  float* out0 = (float*)d_out;               // [B,3,S]
  float* out1 = out0 + (size_t)B_ * 3 * S_;  // [B,Dout,S]

  char* ws = (char*)d_ws;
  int*   fps_idx = (int*)ws;                          // 16 KB
  u16*   wb      = (u16*)(ws + 16384);                // 249856 bf16
  float* fb      = (float*)(ws + 516096);             // 1024 f32 (ends 520192)
  float* dist_ws = (float*)(ws + 520192);             // B*2048 f32 = 64 KB
  int*   far_ws  = (int*)(ws + 585728);               // 8 ints
  const size_t MB = 1024 * 1024;
  u16* x     = (u16*)(ws + 1 * MB);    // [16384][128]
  u16* o     = (u16*)(ws + 5 * MB);    // [B,N,128]
  u16* x2    = (u16*)(ws + 9 * MB);    // [16384][128]
  u16* feats = (u16*)(ws + 13 * MB);   // [16384][128]
  u16* qb    = (u16*)(ws + 17 * MB);   // q|k|v, each [B,H,N,32]
  u16* h     = (u16*)(ws + 29 * MB);   // [16384][512]

  prep_kernel<<<980, 256, 0, stream>>>(Wq, bq, Wk, bk, Wv, bv, Wo, W1, W2, Wfc,
                                       bfc, Wp, bp, Wpos, bpos, g1, be1, m1, v1,
                                       g2, bb2, m2, v2, wb, fb);

  // FPS slices ride along the 6 pipeline kernels: 70|90|100|70|110|72 steps.
  // x = BN1(proj)+pos  (Wcat, bias_x)               + FPS steps [0,70)
  gemm_k<96, 96, 1, 0><<<8 + 128, 256, 0, stream>>>(
      nullptr, wb + OW_CAT, points, xyz, nullptr, fb + 384, nullptr, nullptr,
      nullptr, x, nullptr, 1, 8, 0, 70, xyz, dist_ws, far_ws, fps_idx, out0);
  // qkv                                             + FPS steps [70,160)
  gemm_k<128, 128, 0, 1><<<8 + 384, 256, 0, stream>>>(
      x, wb + OW_QKV, nullptr, nullptr, nullptr, fb, nullptr, nullptr,
      nullptr, qb, nullptr, 3, 8, 70, 160, xyz, dist_ws, far_ws, fps_idx, out0);
  // attention                                       + FPS steps [160,260)
  attn_mfma_kernel<<<8 + B_ * H_ * (N_ / 128), 256, 0, stream>>>(
      qb, qb + 2097152, qb + 2 * 2097152, o, 8, 160, 260, xyz, dist_ws, far_ws,
      fps_idx, out0);
  // x2 = LN1(x + o@Wo^T + bo)                       + FPS steps [260,330)
  gemm_k<128, 128, 0, 3><<<8 + 128, 256, 0, stream>>>(
      o, wb + OW_O, nullptr, nullptr, nullptr, bo, lg1, lb1, x, x2, nullptr, 1,
      8, 260, 330, xyz, dist_ws, far_ws, fps_idx, out0);
  // h = relu(x2@W1^T + b1)                          + FPS steps [330,440)
  gemm_k<128, 128, 0, 2><<<8 + 512, 256, 0, stream>>>(
      x2, wb + OW_1, nullptr, nullptr, nullptr, b1, nullptr, nullptr,
      nullptr, h, nullptr, 4, 8, 330, 440, xyz, dist_ws, far_ws, fps_idx, out0);
  // feats = LN2(x2 + h@W2^T + b2)                   + FPS steps [440,512)
  gemm_k<512, 128, 0, 3><<<8 + 128, 256, 0, stream>>>(
      h, wb + OW_2, nullptr, nullptr, nullptr, b2p, lg2, lb2, x2, feats,
      nullptr, 1, 8, 440, 512, xyz, dist_ws, far_ws, fps_idx, out0);
  // out1 = relu(BN2(gather(feats,xyz)@Wfc^T + bfc))  (no FPS blocks)
  gemm_k<160, 160, 2, 4><<<64, 256, 0, stream>>>(
      feats, wb + OW_FC, nullptr, xyz, fps_idx, nullptr, fb + 512, fb + 768,
      nullptr, nullptr, out1, 2, 0, 0, 0, nullptr, nullptr, nullptr, nullptr,
      nullptr);
}

// Round 6
// 360.563 us; speedup vs baseline: 8.5378x; 1.0183x over previous
//
#include <hip/hip_runtime.h>
#include <hip/hip_bf16.h>

#define B_    8
#define N_    2048
#define CIN_  64
#define D_    128
#define DFF_  512
#define DOUT_ 256
#define S_    512
#define H_    4
#define HD_   32
#define EPS_  1e-5f

typedef unsigned short u16;
typedef unsigned long long u64;
typedef __attribute__((ext_vector_type(8))) short short8v;  // 8 bf16
typedef __attribute__((ext_vector_type(4))) float f32x4;

__device__ __forceinline__ u16 f2bu(float f) {
  __hip_bfloat16 h = __float2bfloat16(f);
  return *(u16*)&h;
}
__device__ __forceinline__ float bu2f(u16 u) {
  __hip_bfloat16 h = *(__hip_bfloat16*)&u;
  return __bfloat162float(h);
}

// ---------------------------------------------------------------------------
// Weight prep: fold BN1 into W_proj, 1/sqrt(hd) into Wq/bq, BN2 into
// scale/shift; convert all GEMM weights to bf16 (padded K where needed).
// ---------------------------------------------------------------------------
#define OW_QKV 0
#define OW_O   49152
#define OW_1   65536
#define OW_2   131072
#define OW_FC  196608
#define OW_CAT 237568
#define NW_TOT 249856

__global__ __launch_bounds__(256) void prep_kernel(
    const float* __restrict__ Wq, const float* __restrict__ bq,
    const float* __restrict__ Wk, const float* __restrict__ bk,
    const float* __restrict__ Wv, const float* __restrict__ bv,
    const float* __restrict__ Wo, const float* __restrict__ W1,
    const float* __restrict__ W2, const float* __restrict__ Wfc,
    const float* __restrict__ bfc, const float* __restrict__ Wp,
    const float* __restrict__ bp, const float* __restrict__ Wpos,
    const float* __restrict__ bpos, const float* __restrict__ g1,
    const float* __restrict__ be1, const float* __restrict__ m1,
    const float* __restrict__ v1, const float* __restrict__ g2,
    const float* __restrict__ bb2, const float* __restrict__ m2,
    const float* __restrict__ v2, u16* __restrict__ wb,
    float* __restrict__ fb) {
  const float SC = 0.1767766952966369f;  // 1/sqrt(32)
  int i = blockIdx.x * 256 + threadIdx.x;
  if (i < OW_O) {  // Wqkv [384][128]
    int n = i >> 7, k = i & 127;
    float v = (n < 128) ? Wq[i] * SC
                        : (n < 256) ? Wk[(n - 128) * 128 + k]
                                    : Wv[(n - 256) * 128 + k];
    wb[OW_QKV + i] = f2bu(v);
  } else if (i < OW_1) {
    wb[i] = f2bu(Wo[i - OW_O]);
  } else if (i < OW_2) {
    wb[i] = f2bu(W1[i - OW_1]);
  } else if (i < OW_FC) {
    wb[i] = f2bu(W2[i - OW_2]);
  } else if (i < OW_CAT) {  // Wfc [256][160] (pad 131->160)
    int j = i - OW_FC;
    int n = j / 160, c = j % 160;
    wb[i] = f2bu(c < 131 ? Wfc[n * 131 + c] : 0.f);
  } else if (i < NW_TOT) {  // Wcat [128][96]: BN1-scaled Wp | Wpos | 0
    int j = i - OW_CAT;
    int d = j / 96, c = j % 96;
    float v;
    if (c < 64) v = Wp[d * 64 + c] * (g1[d] * rsqrtf(v1[d] + EPS_));
    else if (c < 67) v = Wpos[d * 3 + (c - 64)];
    else v = 0.f;
    wb[i] = f2bu(v);
  } else if (i < NW_TOT + 384) {  // bqkv
    int n = i - NW_TOT;
    fb[n] = (n < 128) ? bq[n] * SC : (n < 256) ? bk[n - 128] : bv[n - 256];
  } else if (i < NW_TOT + 512) {  // bias_x
    int d = i - (NW_TOT + 384);
    float s1 = g1[d] * rsqrtf(v1[d] + EPS_);
    fb[384 + d] = (bp[d] - m1[d]) * s1 + be1[d] + bpos[d];
  } else if (i < NW_TOT + 768) {  // fc_scale
    int n = i - (NW_TOT + 512);
    fb[512 + n] = g2[n] * rsqrtf(v2[n] + EPS_);
  } else if (i < NW_TOT + 1024) {  // fc_shift
    int n = i - (NW_TOT + 768);
    float s = g2[n] * rsqrtf(v2[n] + EPS_);
    fb[768 + n] = bfc[n] * s + bb2[n] - m2[n] * s;
  }
}

// ---------------------------------------------------------------------------
// FPS slice: steps [s0,s1) for batch b, hosted as extra blocks in pipeline
// kernels (state in d_ws). numpy-exact f32 arithmetic, first-occurrence
// argmax. Winner lane broadcasts key AND coords via LDS (read in parallel
// after one raw s_barrier; no vmcnt drain, no dependent xs[far] lookup).
// LDS need: 256 B.
// ---------------------------------------------------------------------------
#define FPS_SMEM 256

template <int CTRL, int RM>
__device__ __forceinline__ float dppmax(float v) {
  int m = __builtin_amdgcn_update_dpp(__float_as_int(v), __float_as_int(v),
                                      CTRL, RM, 0xF, true);
  return fmaxf(v, __int_as_float(m));
}

__device__ __forceinline__ void fps_slice(
    char* smem, int b, const float* __restrict__ xyz,
    float* __restrict__ dist_ws, int* __restrict__ far_ws,
    int* __restrict__ idx_out, float* __restrict__ out0, int s0, int s1) {
  u64* keys = (u64*)smem;            // [2][4]
  float* crd = (float*)(smem + 64);  // [2][4][3]
  const int t = threadIdx.x, w = t >> 6, lane = t & 63;
  const float* xb = xyz + (size_t)b * 3 * N_;
  const int base = w * 512 + lane * 8;
  float* dw = dist_ws + b * N_;
  float px[8], py[8], pz[8], dist[8];
#pragma unroll
  for (int j = 0; j < 8; j++) {
    px[j] = xb[base + j];
    py[j] = xb[N_ + base + j];
    pz[j] = xb[2 * N_ + base + j];
    dist[j] = 1e10f;
  }
  if (s0 != 0) {
#pragma unroll
    for (int j = 0; j < 8; j++) dist[j] = dw[base + j];
  }
  int far = (s0 == 0) ? 0 : far_ws[b];
  float cx = xb[far], cy = xb[N_ + far], cz = xb[2 * N_ + far];
  for (int s = s0; s < s1; s++) {
    if (t == 0) {
      idx_out[b * S_ + s] = far;
      out0[(size_t)b * 3 * S_ + s] = cx;
      out0[(size_t)b * 3 * S_ + S_ + s] = cy;
      out0[(size_t)b * 3 * S_ + 2 * S_ + s] = cz;
    }
    float best = -1.0f, bx = 0.f, by = 0.f, bz = 0.f;
    int bestp = 0;
#pragma unroll
    for (int j = 0; j < 8; j++) {
      float dx = __fsub_rn(px[j], cx);
      float dy = __fsub_rn(py[j], cy);
      float dz = __fsub_rn(pz[j], cz);
      float d = __fadd_rn(__fadd_rn(__fmul_rn(dx, dx), __fmul_rn(dy, dy)),
                          __fmul_rn(dz, dz));
      float nd = fminf(dist[j], d);
      dist[j] = nd;
      if (nd > best) {
        best = nd; bestp = base + j;  // ascending j: first max
        bx = px[j]; by = py[j]; bz = pz[j];
      }
    }
    // wave-wide max (value) via DPP; lane 63 holds the wave max
    float m = best;
    m = dppmax<0x111, 0xF>(m);  // row_shr:1
    m = dppmax<0x112, 0xF>(m);  // row_shr:2
    m = dppmax<0x114, 0xF>(m);  // row_shr:4
    m = dppmax<0x118, 0xF>(m);  // row_shr:8
    m = dppmax<0x142, 0xA>(m);  // row_bcast:15
    m = dppmax<0x143, 0xC>(m);  // row_bcast:31
    float M = __int_as_float(__builtin_amdgcn_readlane(__float_as_int(m), 63));
    u64 mask = __ballot(best == M);
    int wl = __ffsll((long long)mask) - 1;  // first lane = smallest point idx
    if (lane == wl) {
      int sb = (s & 1) * 4 + w;
      keys[sb] = ((u64)__float_as_uint(M) << 32) |
                 (unsigned)(0xFFFFFFFFu - (unsigned)bestp);
      crd[sb * 3 + 0] = bx;
      crd[sb * 3 + 1] = by;
      crd[sb * 3 + 2] = bz;
    }
    asm volatile("s_waitcnt lgkmcnt(0)" ::: "memory");
    __builtin_amdgcn_s_barrier();
    asm volatile("" ::: "memory");
    const int q0 = (s & 1) * 4;
    u64 k0 = keys[q0], k1 = keys[q0 + 1], k2 = keys[q0 + 2], k3 = keys[q0 + 3];
    float x0 = crd[q0 * 3 + 0], y0 = crd[q0 * 3 + 1], z0 = crd[q0 * 3 + 2];
    float x1 = crd[q0 * 3 + 3], y1 = crd[q0 * 3 + 4], z1 = crd[q0 * 3 + 5];
    float x2 = crd[q0 * 3 + 6], y2 = crd[q0 * 3 + 7], z2 = crd[q0 * 3 + 8];
    float x3 = crd[q0 * 3 + 9], y3 = crd[q0 * 3 + 10], z3 = crd[q0 * 3 + 11];
    bool c01 = k0 >= k1;
    u64 ka = c01 ? k0 : k1;
    float xa = c01 ? x0 : x1, ya = c01 ? y0 : y1, za = c01 ? z0 : z1;
    bool c23 = k2 >= k3;
    u64 kb = c23 ? k2 : k3;
    float xv = c23 ? x2 : x3, yv = c23 ? y2 : y3, zv = c23 ? z2 : z3;
    bool cf = ka >= kb;
    u64 kk = cf ? ka : kb;
    cx = cf ? xa : xv; cy = cf ? ya : yv; cz = cf ? za : zv;
    far = (int)(0xFFFFFFFFu - (unsigned)kk);
  }
#pragma unroll
  for (int j = 0; j < 8; j++) dw[base + j] = dist[j];
  if (t == 0) far_ws[b] = far;
}

// ---------------------------------------------------------------------------
// Tiled bf16 MFMA GEMM template (+ optional FPS co-blocks at blockIdx < fpsnb).
// C[128 x 128] tile per block, 4 waves, 16x16x32 MFMA.
// Frag contract (R3/R4-verified): a[e]=A[l&15][8*(l>>4)+e],
// b[e]=W[l&15][8*(l>>4)+e] (W row-major [N][K]), d[i]=C[4*(l>>4)+i][l&15].
// ---------------------------------------------------------------------------
template <int K, int KC, int ASTAGE, int EPI>
__global__ __launch_bounds__(256) void gemm_k(
    const u16* __restrict__ A, const u16* __restrict__ W,
    const float* __restrict__ srcf0, const float* __restrict__ srcf1,
    const int* __restrict__ fidx, const float* __restrict__ p0,
    const float* __restrict__ p1, const float* __restrict__ p2,
    const u16* __restrict__ resid, u16* __restrict__ outb,
    float* __restrict__ outf, int ntn, int fpsnb, int s0, int s1,
    const float* fxyz, float* fdist, int* ffar, int* fidxo, float* fout0) {
  constexpr int KP = KC + 8;
  constexpr int GEMM_SMEM = 2 * 128 * KP * 2;
  constexpr int SMEM = GEMM_SMEM > FPS_SMEM ? GEMM_SMEM : FPS_SMEM;
  __shared__ __align__(16) char smem[SMEM];
  if ((int)blockIdx.x < fpsnb) {
    fps_slice(smem, blockIdx.x, fxyz, fdist, ffar, fidxo, fout0, s0, s1);
    return;
  }
  u16 (*As)[KP] = (u16 (*)[KP])smem;
  u16 (*Ws)[KP] = (u16 (*)[KP])(smem + 128 * KP * 2);
  const int bid = blockIdx.x - fpsnb;
  const int mt = bid / ntn, nt = bid % ntn;
  const int t = threadIdx.x, w = t >> 6, lane = t & 63;
  const int g = lane >> 4, lr = lane & 15;

  f32x4 acc[2][8];
#pragma unroll
  for (int qf = 0; qf < 2; qf++)
#pragma unroll
    for (int nf = 0; nf < 8; nf++) acc[qf][nf] = {0.f, 0.f, 0.f, 0.f};

  for (int kc = 0; kc < K / KC; kc++) {
    __syncthreads();
    for (int i = t; i < 128 * (KC / 8); i += 256) {
      int row = i / (KC / 8), c8 = i % (KC / 8);
      *(short8v*)&Ws[row][c8 * 8] =
          *(const short8v*)(W + (size_t)(nt * 128 + row) * K + kc * KC + c8 * 8);
    }
    if constexpr (ASTAGE == 0) {
      for (int i = t; i < 128 * (KC / 8); i += 256) {
        int row = i / (KC / 8), c8 = i % (KC / 8);
        *(short8v*)&As[row][c8 * 8] =
            *(const short8v*)(A + (size_t)(mt * 128 + row) * K + kc * KC + c8 * 8);
      }
    } else if constexpr (ASTAGE == 1) {
      int bb = (mt * 128) >> 11, n0 = (mt * 128) & (N_ - 1);
      for (int i = t; i < 96 * 128; i += 256) {
        int c = i >> 7, n = i & 127;
        float v;
        if (c < 64) v = srcf0[((size_t)bb * CIN_ + c) * N_ + n0 + n];
        else if (c < 67) v = srcf1[((size_t)bb * 3 + (c - 64)) * N_ + n0 + n];
        else v = 0.f;
        As[n][c] = f2bu(v);
      }
    } else {  // ASTAGE == 2
      int bb = (mt * 128) >> 9, sq0 = (mt * 128) & (S_ - 1);
      for (int i = t; i < 128 * 20; i += 256) {
        int row = i / 20, c8 = i % 20;
        int id = fidx[bb * S_ + sq0 + row];
        short8v val;
        if (c8 < 16) {
          val = *(const short8v*)(A + ((size_t)bb * N_ + id) * D_ + c8 * 8);
        } else if (c8 == 16) {
          val = short8v{0, 0, 0, 0, 0, 0, 0, 0};
          val[0] = (short)f2bu(srcf1[((size_t)bb * 3 + 0) * N_ + id]);
          val[1] = (short)f2bu(srcf1[((size_t)bb * 3 + 1) * N_ + id]);
          val[2] = (short)f2bu(srcf1[((size_t)bb * 3 + 2) * N_ + id]);
        } else {
          val = short8v{0, 0, 0, 0, 0, 0, 0, 0};
        }
        *(short8v*)&As[row][c8 * 8] = val;
      }
    }
    __syncthreads();
#pragma unroll
    for (int ks = 0; ks < KC / 32; ks++) {
      short8v a0 = *(const short8v*)&As[w * 32 + lr][ks * 32 + 8 * g];
      short8v a1 = *(const short8v*)&As[w * 32 + 16 + lr][ks * 32 + 8 * g];
#pragma unroll
      for (int nf = 0; nf < 8; nf++) {
        short8v bb = *(const short8v*)&Ws[nf * 16 + lr][ks * 32 + 8 * g];
        acc[0][nf] = __builtin_amdgcn_mfma_f32_16x16x32_bf16(a0, bb, acc[0][nf], 0, 0, 0);
        acc[1][nf] = __builtin_amdgcn_mfma_f32_16x16x32_bf16(a1, bb, acc[1][nf], 0, 0, 0);
      }
    }
  }

  if constexpr (EPI == 3) {  // bias + residual + LayerNorm (ntn==1)
#pragma unroll
    for (int qf = 0; qf < 2; qf++) {
#pragma unroll
      for (int i = 0; i < 4; i++) {
        int m = mt * 128 + w * 32 + qf * 16 + 4 * g + i;
        float v[8], sm = 0.f, sq = 0.f;
#pragma unroll
        for (int nf = 0; nf < 8; nf++) {
          int n = nf * 16 + lr;
          float x = acc[qf][nf][i] + p0[n] + bu2f(resid[(size_t)m * D_ + n]);
          v[nf] = x;
          sm += x;
          sq += x * x;
        }
#pragma unroll
        for (int msk = 1; msk < 16; msk <<= 1) {
          sm += __shfl_xor(sm, msk);
          sq += __shfl_xor(sq, msk);
        }
        float mu = sm * (1.f / 128.f);
        float var = sq * (1.f / 128.f) - mu * mu;
        float rs = rsqrtf(var + EPS_);
#pragma unroll
        for (int nf = 0; nf < 8; nf++) {
          int n = nf * 16 + lr;
          outb[(size_t)m * D_ + n] = f2bu((v[nf] - mu) * rs * p1[n] + p2[n]);
        }
      }
    }
  } else {
#pragma unroll
    for (int qf = 0; qf < 2; qf++)
#pragma unroll
      for (int nf = 0; nf < 8; nf++)
#pragma unroll
        for (int i = 0; i < 4; i++) {
          int m = mt * 128 + w * 32 + qf * 16 + 4 * g + i;
          int nl = nf * 16 + lr;
          int n = nt * 128 + nl;
          float vv = acc[qf][nf][i];
          if constexpr (EPI == 0) {
            outb[(size_t)m * D_ + nl] = f2bu(vv + p0[n]);
          } else if constexpr (EPI == 1) {
            vv += p0[n];
            int which = n >> 7, h = (n >> 5) & 3, c = n & 31;
            int bb = m >> 11, tok = m & (N_ - 1);
            outb[(size_t)which * 2097152 +
                 (((size_t)bb * H_ + h) * N_ + tok) * HD_ + c] = f2bu(vv);
          } else if constexpr (EPI == 2) {
            outb[(size_t)m * DFF_ + n] = f2bu(fmaxf(vv + p0[n], 0.f));
          } else {  // EPI == 4
            float r = fmaxf(vv * p1[n] + p2[n], 0.f);
            outf[((size_t)(m >> 9) * DOUT_ + n) * S_ + (m & (S_ - 1))] = r;
          }
        }
  }
}

// ---------------------------------------------------------------------------
// Flash attention, swapped-QK^T form. Grid: 32 bh x 32 q-tiles of 64 rows.
// Block: 4 waves, 16 q-rows/wave (q = lane&15 -> per-lane softmax scalars).
// QK^T: S^T = mfma(Kfrag, Qfrag); softmax reduce = 2 shfl_xor (16,32).
// P packed to ps[q][k] via 4x ds_write_b64; PV: O^T = mfma(V^T, P^T) with
// b128 reads; output q = lane&15 keeps rescale/div lane-local.
// ---------------------------------------------------------------------------
__global__ __launch_bounds__(256) void attn_mfma_kernel(
    const u16* __restrict__ qg, const u16* __restrict__ kg,
    const u16* __restrict__ vg, u16* __restrict__ o, int fpsnb, int s0, int s1,
    const float* fxyz, float* fdist, int* ffar, int* fidxo, float* fout0) {
  constexpr int ATTN_SMEM = 64 * 40 * 2 + 32 * 72 * 2 + 4 * 16 * 72 * 2;
  constexpr int SMEM = ATTN_SMEM > FPS_SMEM ? ATTN_SMEM : FPS_SMEM;
  __shared__ __align__(16) char smem[SMEM];
  if ((int)blockIdx.x < fpsnb) {
    fps_slice(smem, blockIdx.x, fxyz, fdist, ffar, fidxo, fout0, s0, s1);
    return;
  }
  const int t = threadIdx.x;
  const int w = t >> 6, lane = t & 63, g = lane >> 4, lr = lane & 15;
  u16 (*ks)[40] = (u16 (*)[40])smem;                            // K [64][40]
  u16 (*vt)[72] = (u16 (*)[72])(smem + 5120);                   // V^T [32][72]
  u16 (*psw)[72] = (u16 (*)[72])(smem + 9728) + w * 16;         // P [16][72]/wave

  const int bid = blockIdx.x - fpsnb;
  const int qt = bid & 31;
  const int bh = bid >> 5;
  const int b = bh >> 2, h = bh & 3;
  const int qrow = qt * 64 + w * 16 + lr;  // this lane's q row

  // Q fragment: a[e]=Q[q=lr(+base)][8g+e]; serves as B-frag (=Q^T) for S^T.
  short8v aq = *(const short8v*)(qg + ((size_t)bh * N_ + qrow) * HD_ + 8 * g);

  const u16* kb = kg + (size_t)bh * N_ * HD_;
  const u16* vb = vg + (size_t)bh * N_ * HD_;

  const f32x4 fzero = {0.f, 0.f, 0.f, 0.f};
  float mrun = -INFINITY, lrun = 0.f;
  f32x4 acco[2] = {fzero, fzero};  // O^T cols q=lr, rows d=16dt+4g+i

  const int srow = t >> 2, scol = (t & 3) * 8;

  for (int ch = 0; ch < 32; ch++) {
    __syncthreads();
    short8v kvv = *(const short8v*)(kb + (size_t)(ch * 64 + srow) * HD_ + scol);
    short8v vvv = *(const short8v*)(vb + (size_t)(ch * 64 + srow) * HD_ + scol);
    *(short8v*)(&ks[srow][scol]) = kvv;
#pragma unroll
    for (int e = 0; e < 8; e++) vt[scol + e][srow] = (u16)vvv[e];
    __syncthreads();

    // S^T = K x Q^T: st[kt][i] = S^T[key=16kt+4g+i][q=lr]
    f32x4 st[4];
#pragma unroll
    for (int kt = 0; kt < 4; kt++) {
      short8v ak = *(const short8v*)(&ks[kt * 16 + lr][8 * g]);
      st[kt] = __builtin_amdgcn_mfma_f32_16x16x32_bf16(ak, aq, fzero, 0, 0, 0);
    }

    // online softmax for q=lr: 16 in-reg values + 2 shfl (over g)
    float mx = -INFINITY;
#pragma unroll
    for (int kt = 0; kt < 4; kt++)
#pragma unroll
      for (int i = 0; i < 4; i++) mx = fmaxf(mx, st[kt][i]);
    mx = fmaxf(mx, __shfl_xor(mx, 16));
    mx = fmaxf(mx, __shfl_xor(mx, 32));
    float nm = fmaxf(mrun, mx);
    float alpha = __expf(mrun - nm);
    mrun = nm;
    float psum = 0.f;
#pragma unroll
    for (int kt = 0; kt < 4; kt++) {
      float p0 = __expf(st[kt][0] - nm);
      float p1 = __expf(st[kt][1] - nm);
      float p2 = __expf(st[kt][2] - nm);
      float p3 = __expf(st[kt][3] - nm);
      psum += (p0 + p1) + (p2 + p3);
      u64 pk = (u64)f2bu(p0) | ((u64)f2bu(p1) << 16) |
               ((u64)f2bu(p2) << 32) | ((u64)f2bu(p3) << 48);
      *(u64*)(&psw[lr][kt * 16 + 4 * g]) = pk;  // P[q=lr][k=16kt+4g..+3]
    }
    psum += __shfl_xor(psum, 16);
    psum += __shfl_xor(psum, 32);
    lrun = lrun * alpha + psum;
#pragma unroll
    for (int dt = 0; dt < 2; dt++)
#pragma unroll
      for (int i = 0; i < 4; i++) acco[dt][i] *= alpha;

    // O^T += V^T x P^T (same-wave psw write->read; compiler inserts lgkmcnt)
#pragma unroll
    for (int mc = 0; mc < 2; mc++) {
      short8v pb = *(const short8v*)(&psw[lr][mc * 32 + 8 * g]);
#pragma unroll
      for (int dt = 0; dt < 2; dt++) {
        short8v av = *(const short8v*)(&vt[dt * 16 + lr][mc * 32 + 8 * g]);
        acco[dt] = __builtin_amdgcn_mfma_f32_16x16x32_bf16(av, pb, acco[dt], 0, 0, 0);
      }
    }
  }

  float rl = 1.0f / lrun;
#pragma unroll
  for (int dt = 0; dt < 2; dt++) {
    u64 pk = (u64)f2bu(acco[dt][0] * rl) | ((u64)f2bu(acco[dt][1] * rl) << 16) |
             ((u64)f2bu(acco[dt][2] * rl) << 32) |
             ((u64)f2bu(acco[dt][3] * rl) << 48);
    *(u64*)(o + ((size_t)b * N_ + qrow) * D_ + h * HD_ + dt * 16 + 4 * g) = pk;
  }
}

// ---------------------------------------------------------------------------
extern "C" void kernel_launch(void* const* d_in, const int* in_sizes, int n_in,
                              void* d_out, int out_size, void* d_ws, size_t ws_size,
                              hipStream_t stream) {
  const float* xyz    = (const float*)d_in[0];
  const float* points = (const float*)d_in[1];
  const float* Wp     = (const float*)d_in[2];
  const float* bp     = (const float*)d_in[3];
  const float* g1     = (const float*)d_in[4];
  const float* be1    = (const float*)d_in[5];
  const float* m1     = (const float*)d_in[6];
  const float* v1     = (const float*)d_in[7];
  const float* Wpos   = (const float*)d_in[8];
  const float* bpos   = (const float*)d_in[9];
  const float* Wq     = (const float*)d_in[10];
  const float* bq     = (const float*)d_in[11];
  const float* Wk     = (const float*)d_in[12];
  const float* bk     = (const float*)d_in[13];
  const float* Wv     = (const float*)d_in[14];
  const float* bv     = (const float*)d_in[15];
  const float* Wo     = (const float*)d_in[16];
  const float* bo     = (const float*)d_in[17];
  const float* lg1    = (const float*)d_in[18];
  const float* lb1    = (const float*)d_in[19];
  const float* W1     = (const float*)d_in[20];
  const float* b1     = (const float*)d_in[21];
  const float* W2     = (const float*)d_in[22];
  const float* b2p    = (const float*)d_in[23];
  const float* lg2    = (const float*)d_in[24];
  const float* lb2    = (const float*)d_in[25];
  const float* Wfc    = (const float*)d_in[26];
  const float* bfc    = (const float*)d_in[27];
  const float* g2     = (const float*)d_in[28];
  const float* bb2    = (const float*)d_in[29];
  const float* m2     = (const float*)d_in[30];
  const float* v2     = (const float*)d_in[31];

  float* out0 = (float*)d_out;               // [B,3,S]
  float* out1 = out0 + (size_t)B_ * 3 * S_;  // [B,Dout,S]

  char* ws = (char*)d_ws;
  int*   fps_idx = (int*)ws;                          // 16 KB
  u16*   wb      = (u16*)(ws + 16384);                // 249856 bf16
  float* fb      = (float*)(ws + 516096);             // 1024 f32 (ends 520192)
  float* dist_ws = (float*)(ws + 520192);             // B*2048 f32 = 64 KB
  int*   far_ws  = (int*)(ws + 585728);               // 8 ints
  const size_t MB = 1024 * 1024;
  u16* x     = (u16*)(ws + 1 * MB);    // [16384][128]
  u16* o     = (u16*)(ws + 5 * MB);    // [B,N,128]
  u16* x2    = (u16*)(ws + 9 * MB);    // [16384][128]
  u16* feats = (u16*)(ws + 13 * MB);   // [16384][128]
  u16* qb    = (u16*)(ws + 17 * MB);   // q|k|v, each [B,H,N,32]
  u16* h     = (u16*)(ws + 29 * MB);   // [16384][512]

  prep_kernel<<<980, 256, 0, stream>>>(Wq, bq, Wk, bk, Wv, bv, Wo, W1, W2, Wfc,
                                       bfc, Wp, bp, Wpos, bpos, g1, be1, m1, v1,
                                       g2, bb2, m2, v2, wb, fb);

  // FPS slices ride along the 6 pipeline kernels: 70|90|100|70|110|72 steps.
  gemm_k<96, 96, 1, 0><<<8 + 128, 256, 0, stream>>>(
      nullptr, wb + OW_CAT, points, xyz, nullptr, fb + 384, nullptr, nullptr,
      nullptr, x, nullptr, 1, 8, 0, 70, xyz, dist_ws, far_ws, fps_idx, out0);
  gemm_k<128, 128, 0, 1><<<8 + 384, 256, 0, stream>>>(
      x, wb + OW_QKV, nullptr, nullptr, nullptr, fb, nullptr, nullptr,
      nullptr, qb, nullptr, 3, 8, 70, 160, xyz, dist_ws, far_ws, fps_idx, out0);
  attn_mfma_kernel<<<8 + B_ * H_ * (N_ / 64), 256, 0, stream>>>(
      qb, qb + 2097152, qb + 2 * 2097152, o, 8, 160, 260, xyz, dist_ws, far_ws,
      fps_idx, out0);
  gemm_k<128, 128, 0, 3><<<8 + 128, 256, 0, stream>>>(
      o, wb + OW_O, nullptr, nullptr, nullptr, bo, lg1, lb1, x, x2, nullptr, 1,
      8, 260, 330, xyz, dist_ws, far_ws, fps_idx, out0);
  gemm_k<128, 128, 0, 2><<<8 + 512, 256, 0, stream>>>(
      x2, wb + OW_1, nullptr, nullptr, nullptr, b1, nullptr, nullptr,
      nullptr, h, nullptr, 4, 8, 330, 440, xyz, dist_ws, far_ws, fps_idx, out0);
  gemm_k<512, 128, 0, 3><<<8 + 128, 256, 0, stream>>>(
      h, wb + OW_2, nullptr, nullptr, nullptr, b2p, lg2, lb2, x2, feats,
      nullptr, 1, 8, 440, 512, xyz, dist_ws, far_ws, fps_idx, out0);
  gemm_k<160, 160, 2, 4><<<64, 256, 0, stream>>>(
      feats, wb + OW_FC, nullptr, xyz, fps_idx, nullptr, fb + 512, fb + 768,
      nullptr, nullptr, out1, 2, 0, 0, 0, nullptr, nullptr, nullptr, nullptr,
      nullptr);
}